// Round 5
// baseline (729.747 us; speedup 1.0000x reference)
//
#include <hip/hip_runtime.h>
#include <hip/hip_fp16.h>
#include <math.h>

#define N_NODES 100000
#define N_EDGES 1600000
#define D_IN    256
#define D_HID   128
#define NH      4
#define NF      32
#define D_SEM   128
#define NC      8
#define NEG_SLOPE 0.2f
#define BUCKET  64          // fixed per-dst edge capacity (max degree ~40 for uniform E/N=16)

typedef _Float16 half8 __attribute__((ext_vector_type(8)));
typedef float    floatx4 __attribute__((ext_vector_type(4)));

// ---------------------------------------------------------------------------
// WF[d][p*8 + e*4 + h]:  e=0 -> fold(Wsrc_p, al_p)  (el = x @ WF_el)
//                        e=1 -> fold(Wdst_p, ar_p)  (er = x @ WF_er)
__global__ void prep_fold(const float* __restrict__ Ws0, const float* __restrict__ al0,
                          const float* __restrict__ Wd0, const float* __restrict__ ar0,
                          const float* __restrict__ Ws1, const float* __restrict__ al1,
                          const float* __restrict__ Wd1, const float* __restrict__ ar1,
                          float* __restrict__ WF) {
    int d = threadIdx.x;
    for (int p = 0; p < 2; ++p) {
        const float* Ws = p ? Ws1 : Ws0;
        const float* al = p ? al1 : al0;
        const float* Wd = p ? Wd1 : Wd0;
        const float* ar = p ? ar1 : ar0;
        for (int h = 0; h < NH; ++h) {
            float se = 0.f, sr = 0.f;
            for (int f = 0; f < NF; ++f) {
                se = fmaf(Ws[d*D_HID + h*NF + f], al[h*NF + f], se);
                sr = fmaf(Wd[d*D_HID + h*NF + f], ar[h*NF + f], sr);
            }
            WF[d*16 + p*8 + h]     = se;
            WF[d*16 + p*8 + 4 + h] = sr;
        }
    }
}

// ---------------------------------------------------------------------------
// Pre-transpose + fp16 cast: WT_p[c][k] = Wsrc_p[k][c] (128x256), WP1T[c][k] = Wp1[k][c] (128x128)
__global__ __launch_bounds__(256) void prep_tr(const float* __restrict__ Ws0,
                                               const float* __restrict__ Ws1,
                                               const float* __restrict__ Wp1,
                                               __half* __restrict__ WT0,
                                               __half* __restrict__ WT1,
                                               __half* __restrict__ WP1T) {
    int g = blockIdx.x * 256 + threadIdx.x;
    if (g < 32768) {
        int c = g >> 8, k = g & 255;
        WT0[g] = __float2half_rn(Ws0[k*D_HID + c]);
    } else if (g < 65536) {
        int g2 = g - 32768;
        int c = g2 >> 8, k = g2 & 255;
        WT1[g2] = __float2half_rn(Ws1[k*D_HID + c]);
    } else {
        int g2 = g - 65536;
        int c = g2 >> 7, k = g2 & 127;
        WP1T[g2] = __float2half_rn(Wp1[k*D_SEM + c]);
    }
}

// ---------------------------------------------------------------------------
// One pass over x computing all 16 per-node attention logits, and emitting
// the fp16 copy of x (XH) consumed by both gemm_fs_mfma dispatches.
// eler[(p*2+e)*N*4 + n*4 + h] = sum_d x[n,d] * WF[d][p*8+e*4+h]
__global__ __launch_bounds__(256) void er_el_kernel(const float* __restrict__ x,
                                                    const float* __restrict__ WF,
                                                    float* __restrict__ eler,
                                                    __half* __restrict__ XH) {
    __shared__ float xs[16][260];
    __shared__ float wfs[4096];
    int tid = threadIdx.x;
    #pragma unroll
    for (int i = 0; i < 16; ++i) wfs[tid + i*256] = WF[tid + i*256];
    int n0 = blockIdx.x * 16;
    #pragma unroll
    for (int i = 0; i < 4; ++i) {
        int id = tid + i*256;
        int r = id >> 6, c = (id & 63) << 2;
        *(float4*)&xs[r][c] = *(const float4*)&x[(size_t)(n0 + r)*D_IN + c];
    }
    __syncthreads();
    int node = tid >> 4, c = tid & 15;
    float s = 0.f;
    #pragma unroll 8
    for (int k = 0; k < 256; ++k) s = fmaf(xs[node][k], wfs[k*16 + c], s);
    int p = c >> 3, e = (c >> 2) & 1, h = c & 3;
    eler[(p*2 + e)*400000 + (n0 + node)*4 + h] = s;

    // fp16 copy of the tile (same rounding gemm used before; zero accuracy change)
    #pragma unroll
    for (int i = 0; i < 4; ++i) {
        int id = tid + i*256;
        int r = id >> 6, c4 = (id & 63) << 2;
        float4 v = *(const float4*)&xs[r][c4];
        __half2 h0 = __floats2half2_rn(v.x, v.y);
        __half2 h1 = __floats2half2_rn(v.z, v.w);
        uint2 pk; pk.x = *(unsigned*)&h0; pk.y = *(unsigned*)&h1;
        *(uint2*)&XH[(size_t)(n0 + r)*D_IN + c4] = pk;
    }
}

// ---------------------------------------------------------------------------
// FS = (half)(XH @ W) via v_mfma_f32_16x16x32_f16.  64x128 tile, 4 waves (2x2),
// BK=64 staged per chunk, XOR-swizzled f16 LDS, LDS-transposed coalesced C-write.
__global__ __launch_bounds__(256) void gemm_fs_mfma(const __half* __restrict__ XH, // [N][256] fp16
                                                    const __half* __restrict__ WT, // [128][256] pre-transposed
                                                    __half* __restrict__ FS) {
    __shared__ unsigned short xs[64][64];    // 8 KB, 8 chunks of 8 halves per row
    __shared__ unsigned short ws[128][64];   // 16 KB (reused as C staging)
    int tid = threadIdx.x;
    int row0 = blockIdx.x * 64;
    int wid = tid >> 6, lane = tid & 63;
    int wm = wid >> 1, wn = wid & 1;         // wave tile: rows wm*32.., cols wn*64..
    int lr = lane & 15, lk = lane >> 4;      // lk in 0..3

    floatx4 acc[2][4];
    #pragma unroll
    for (int m = 0; m < 2; ++m)
        #pragma unroll
        for (int n = 0; n < 4; ++n) acc[m][n] = (floatx4){0.f, 0.f, 0.f, 0.f};

    for (int k0 = 0; k0 < D_IN; k0 += 64) {
        // stage x chunk: 64 rows x 64 k halves (16B per thread-item)
        #pragma unroll
        for (int i = 0; i < 2; ++i) {
            int id = tid + i*256;
            int r = id >> 3, c8 = (id & 7) << 3;
            int grow = row0 + r;
            uint4 pk = make_uint4(0u, 0u, 0u, 0u);
            if (grow < N_NODES) pk = *(const uint4*)&XH[(size_t)grow*D_IN + k0 + c8];
            int cc = (((c8 >> 3) ^ (r & 7)) << 3);
            *(uint4*)&xs[r][cc] = pk;
        }
        // stage W chunk: 128 cols x 64 k halves (already fp16, pre-transposed)
        #pragma unroll
        for (int i = 0; i < 8; ++i) {
            int id = tid + i*256;
            int col = id >> 4, c4 = (id & 15) << 2;
            uint2 pk = *(const uint2*)&WT[col*256 + k0 + c4];
            int cc = (((c4 >> 3) ^ (col & 7)) << 3) + (c4 & 7);
            *(uint2*)&ws[col][cc] = pk;
        }
        __syncthreads();
        #pragma unroll
        for (int kk = 0; kk < 2; ++kk) {
            int ksub = kk*4 + lk;            // chunk index 0..7
            half8 a[2], b[4];
            #pragma unroll
            for (int m = 0; m < 2; ++m) {
                int r = wm*32 + m*16 + lr;
                a[m] = *(half8*)&xs[r][((ksub ^ (r & 7)) << 3)];
            }
            #pragma unroll
            for (int n = 0; n < 4; ++n) {
                int c = wn*64 + n*16 + lr;
                b[n] = *(half8*)&ws[c][((ksub ^ (c & 7)) << 3)];
            }
            #pragma unroll
            for (int m = 0; m < 2; ++m)
                #pragma unroll
                for (int n = 0; n < 4; ++n)
                    acc[m][n] = __builtin_amdgcn_mfma_f32_16x16x32_f16(a[m], b[n], acc[m][n], 0, 0, 0);
        }
        __syncthreads();
    }

    // C-write: stage to LDS (reuse ws: 64 rows x 128 cols of halves), then coalesced store
    unsigned short* outs = &ws[0][0];
    #pragma unroll
    for (int m = 0; m < 2; ++m)
        #pragma unroll
        for (int n = 0; n < 4; ++n) {
            int col = wn*64 + n*16 + lr;
            #pragma unroll
            for (int r4 = 0; r4 < 4; ++r4) {
                int rr = wm*32 + m*16 + lk*4 + r4;
                __half hv = __float2half_rn(acc[m][n][r4]);
                outs[rr*128 + col] = *(unsigned short*)&hv;
            }
        }
    __syncthreads();
    #pragma unroll
    for (int i = 0; i < 8; ++i) {
        int id = tid + i*256;
        int r = id >> 5, c4 = (id & 31) << 2;
        int grow = row0 + r;
        if (grow < N_NODES)
            *(uint2*)&FS[(size_t)grow*D_HID + c4] = *(uint2*)&outs[r*128 + c4];
    }
}

// ---------------------------------------------------------------------------
// Direct bucket scatter: one pass over edges, per-node atomic slot counters.
// EDG (25.6 MB) and CNT (400 KB) are LLC-resident; 1.6M 4B scattered writes
// are absorbed by L2/MALL. Replaces the bin+bucket two-pass pipeline.
__global__ __launch_bounds__(256) void scatter_kernel(const int* __restrict__ src,
                                                      const int* __restrict__ dst,
                                                      const float* __restrict__ ew,
                                                      int* __restrict__ cnt,
                                                      unsigned* __restrict__ edg) {
    int i = blockIdx.x * 256 + threadIdx.x;
    int stride = gridDim.x * 256;
    for (int e = i; e < N_EDGES; e += stride) {
        int d = dst[e];
        unsigned q = (unsigned)(ew[e] * 32767.f + 0.5f);
        unsigned rec = ((unsigned)src[e] << 15) | q;   // src<2^17, 17+15=32 bits
        int pos = atomicAdd(&cnt[d], 1);
        if (pos < BUCKET) edg[((size_t)d << 6) + pos] = rec;
    }
}

// ---------------------------------------------------------------------------
__device__ __forceinline__ float coef_of(unsigned w, float v) {
    float a = (float)(w & 32767u) * (1.f / 32767.f);
    v = v > 0.f ? v : NEG_SLOPE * v;
    return a * __builtin_amdgcn_rcpf(1.f + __expf(-v));
}

// Atomic-free aggregation, fully front-loaded metadata:
//  - whole bucket's edge words (4 predicated loads) and el values (4 scalar
//    gathers, one per lane's (edge,head)) issued upfront -> ONE latency round;
//  - all 256 (edge,head) coefficients computed in one shot (lane = e*4+h per
//    16-edge phase), zero redundancy;
//  - FMA stream: 4 phases x 4 edges, pure shfl + predicated FS gather + FMA,
//    4 loads in flight; phases skipped by wave-uniform branch (cn uniform).
__global__ __launch_bounds__(256) void agg_kernel(const __half* __restrict__ FS,
                                                  const float* __restrict__ el,
                                                  const float* __restrict__ er,
                                                  const int* __restrict__ cnt,
                                                  const unsigned* __restrict__ edg,
                                                  const float* __restrict__ bias,
                                                  __half* __restrict__ zh) {
    int wv = (blockIdx.x * 256 + threadIdx.x) >> 6;
    int lane = threadIdx.x & 63;
    if (wv >= N_NODES) return;
    int q   = lane >> 4;         // edge sub-slot 0..3
    int ql  = lane & 15;         // covers feats [8ql, 8ql+8)
    int hh  = lane & 3;          // head of the coefficient this lane computes
    int eL  = lane >> 2;         // edge (within a 16-edge phase) this lane covers
    int cn = cnt[wv];
    if (cn > BUCKET) cn = BUCKET;
    int beg = wv << 6;
    const __half* fsq = FS + (ql << 3);

    // ---- front-loaded metadata (all loads independent, in flight together)
    unsigned w0 = 0, w1 = 0, w2 = 0, w3 = 0;
    if (eL      < cn) w0 = edg[beg + eL];
    if (eL + 16 < cn) w1 = edg[beg + 16 + eL];
    if (eL + 32 < cn) w2 = edg[beg + 32 + eL];
    if (eL + 48 < cn) w3 = edg[beg + 48 + eL];
    int s0v = (int)(w0 >> 15), s1v = (int)(w1 >> 15);
    int s2v = (int)(w2 >> 15), s3v = (int)(w3 >> 15);
    float el0 = el[s0v*4 + hh];
    float el1 = el[s1v*4 + hh];
    float el2 = el[s2v*4 + hh];
    float el3 = el[s3v*4 + hh];
    float erh = er[wv*4 + hh];
    float c0v = (eL      < cn) ? coef_of(w0, el0 + erh) : 0.f;
    float c1v = (eL + 16 < cn) ? coef_of(w1, el1 + erh) : 0.f;
    float c2v = (eL + 32 < cn) ? coef_of(w2, el2 + erh) : 0.f;
    float c3v = (eL + 48 < cn) ? coef_of(w3, el3 + erh) : 0.f;

    float4 a0 = make_float4(0.f,0.f,0.f,0.f);
    float4 a1 = make_float4(0.f,0.f,0.f,0.f);
    int qsh = q << 2, hsel = ql >> 2;

#define AGG_PHASE(SP, CP, BASE)                                               \
    if ((BASE) < cn) {                                                        \
        _Pragma("unroll")                                                     \
        for (int u = 0; u < 4; ++u) {                                         \
            int lsrc = (u << 4) | qsh;                                        \
            int ssrc = __shfl(SP, lsrc);                                      \
            float av = __shfl(CP, lsrc | hsel);                               \
            uint4 raw = make_uint4(0u,0u,0u,0u);                              \
            if ((BASE) + (u << 2) + q < cn)                                   \
                raw = *(const uint4*)&fsq[(size_t)ssrc * D_HID];              \
            float2 f0 = __half22float2(*(__half2*)&raw.x);                    \
            float2 f1 = __half22float2(*(__half2*)&raw.y);                    \
            float2 f2 = __half22float2(*(__half2*)&raw.z);                    \
            float2 f3 = __half22float2(*(__half2*)&raw.w);                    \
            a0.x = fmaf(f0.x, av, a0.x); a0.y = fmaf(f0.y, av, a0.y);         \
            a0.z = fmaf(f1.x, av, a0.z); a0.w = fmaf(f1.y, av, a0.w);         \
            a1.x = fmaf(f2.x, av, a1.x); a1.y = fmaf(f2.y, av, a1.y);         \
            a1.z = fmaf(f3.x, av, a1.z); a1.w = fmaf(f3.y, av, a1.w);         \
        }                                                                     \
    }
    AGG_PHASE(s0v, c0v, 0)
    AGG_PHASE(s1v, c1v, 16)
    AGG_PHASE(s2v, c2v, 32)
    AGG_PHASE(s3v, c3v, 48)
#undef AGG_PHASE

    #pragma unroll
    for (int o = 16; o < 64; o <<= 1) {
        a0.x += __shfl_xor(a0.x, o); a0.y += __shfl_xor(a0.y, o);
        a0.z += __shfl_xor(a0.z, o); a0.w += __shfl_xor(a0.w, o);
        a1.x += __shfl_xor(a1.x, o); a1.y += __shfl_xor(a1.y, o);
        a1.z += __shfl_xor(a1.z, o); a1.w += __shfl_xor(a1.w, o);
    }

    if (q < 2) {
        int c = (ql << 3) + (q << 2);
        float4 r = q ? a1 : a0;
        float4 bv = *(const float4*)&bias[c];
        r.x += bv.x; r.y += bv.y; r.z += bv.z; r.w += bv.w;
        r.x = r.x > 0.f ? r.x : expm1f(r.x);
        r.y = r.y > 0.f ? r.y : expm1f(r.y);
        r.z = r.z > 0.f ? r.z : expm1f(r.z);
        r.w = r.w > 0.f ? r.w : expm1f(r.w);
        __half2 h0 = __floats2half2_rn(r.x, r.y);
        __half2 h1 = __floats2half2_rn(r.z, r.w);
        uint2 pk; pk.x = *(unsigned*)&h0; pk.y = *(unsigned*)&h1;
        *(uint2*)&zh[(size_t)wv*D_HID + c] = pk;
    }
}

// ---------------------------------------------------------------------------
// Semantic attention scores via MFMA: per block sum of tanh(z@Wp1 + bp1)@Wp2
// over a 64-row tile; one atomicAdd per block into wsum[path]. z is f16.
__global__ __launch_bounds__(256) void sem_mfma(const __half* __restrict__ zh0,
                                                const __half* __restrict__ zh1,
                                                const __half* __restrict__ WP1T, // [128][128] pre-transposed
                                                const float* __restrict__ bp1,
                                                const float* __restrict__ Wp2,
                                                float* __restrict__ wsum) {
    __shared__ unsigned short zs[64][128];    // 16 KB, 16 chunks/row
    __shared__ unsigned short ps[128][128];   // 32 KB
    __shared__ float red[4];
    const __half* z = blockIdx.y ? zh1 : zh0;
    int tid = threadIdx.x;
    int row0 = blockIdx.x * 64;
    int wid = tid >> 6, lane = tid & 63;
    int wm = wid >> 1, wn = wid & 1;
    int lr = lane & 15, lk = lane >> 4;

    // stage z tile (f16 direct), 1024 uint4
    #pragma unroll
    for (int i = 0; i < 4; ++i) {
        int id = tid + i*256;
        int r = id >> 4, ch = id & 15;        // 8-half chunk index
        int grow = row0 + r;
        uint4 pk = make_uint4(0u, 0u, 0u, 0u);
        if (grow < N_NODES) pk = *(const uint4*)&z[(size_t)grow*D_HID + (ch << 3)];
        *(uint4*)&zs[r][((ch ^ (r & 7)) << 3)] = pk;
    }
    // stage Wp1T (whole K), 4096 uint2
    #pragma unroll
    for (int i = 0; i < 16; ++i) {
        int id = tid + i*256;
        int c = id >> 5, k4 = (id & 31) << 2;
        uint2 pk = *(const uint2*)&WP1T[c*128 + k4];
        int cc = (((k4 >> 3) ^ (c & 7)) << 3) + (k4 & 7);
        *(uint2*)&ps[c][cc] = pk;
    }
    __syncthreads();

    floatx4 acc[2][4];
    #pragma unroll
    for (int m = 0; m < 2; ++m)
        #pragma unroll
        for (int n = 0; n < 4; ++n) acc[m][n] = (floatx4){0.f, 0.f, 0.f, 0.f};

    #pragma unroll
    for (int kk = 0; kk < 4; ++kk) {
        int ksub = kk*4 + lk;                 // 0..15
        half8 a[2], b[4];
        #pragma unroll
        for (int m = 0; m < 2; ++m) {
            int r = wm*32 + m*16 + lr;
            a[m] = *(half8*)&zs[r][((ksub ^ (r & 7)) << 3)];
        }
        #pragma unroll
        for (int n = 0; n < 4; ++n) {
            int c = wn*64 + n*16 + lr;
            b[n] = *(half8*)&ps[c][((ksub ^ (c & 7)) << 3)];
        }
        #pragma unroll
        for (int m = 0; m < 2; ++m)
            #pragma unroll
            for (int n = 0; n < 4; ++n)
                acc[m][n] = __builtin_amdgcn_mfma_f32_16x16x32_f16(a[m], b[n], acc[m][n], 0, 0, 0);
    }

    // epilogue: s = sum over tile of tanh(acc + bp1[col]) * Wp2[col]
    float s = 0.f;
    #pragma unroll
    for (int m = 0; m < 2; ++m)
        #pragma unroll
        for (int n = 0; n < 4; ++n) {
            int col = wn*64 + n*16 + lr;
            float bp = bp1[col];
            float w2 = Wp2[col];
            #pragma unroll
            for (int r4 = 0; r4 < 4; ++r4) {
                int grow = row0 + wm*32 + m*16 + lk*4 + r4;
                if (grow < N_NODES) {
                    float v = acc[m][n][r4] + bp;
                    float t = 1.f - 2.f / (__expf(2.f*v) + 1.f);
                    s = fmaf(t, w2, s);
                }
            }
        }
    #pragma unroll
    for (int o = 1; o < 64; o <<= 1) s += __shfl_xor(s, o);
    if (lane == 0) red[wid] = s;
    __syncthreads();
    if (tid == 0) atomicAdd(&wsum[blockIdx.y], red[0] + red[1] + red[2] + red[3]);
}

// ---------------------------------------------------------------------------
// out[n,c] = bo[c] + sum_k (b0*z0[n,k] + b1*z1[n,k]) * Wo[k,c]; z inputs f16.
__global__ __launch_bounds__(256) void final_kernel(const __half* __restrict__ zh0,
                                                    const __half* __restrict__ zh1,
                                                    const float* __restrict__ Wo,
                                                    const float* __restrict__ bo,
                                                    const float* __restrict__ wsum,
                                                    float* __restrict__ out) {
    __shared__ float z0s[32][132];
    __shared__ float z1s[32][132];
    __shared__ float wos[128*8];
    __shared__ float bos[8];
    int tid = threadIdx.x;
    int n0 = blockIdx.x * 32;
    #pragma unroll
    for (int i = 0; i < 4; ++i) wos[tid + i*256] = Wo[tid + i*256];
    if (tid < 8) bos[tid] = bo[tid];
    #pragma unroll
    for (int i = 0; i < 2; ++i) {
        int id = tid + i*256;                 // 512 items: 32 rows x 16 chunks
        int r = id >> 4, c8 = (id & 15) << 3;
        uint4 p0 = *(const uint4*)&zh0[(size_t)(n0 + r)*D_HID + c8];
        uint4 p1 = *(const uint4*)&zh1[(size_t)(n0 + r)*D_HID + c8];
        float2 q0 = __half22float2(*(__half2*)&p0.x);
        float2 q1 = __half22float2(*(__half2*)&p0.y);
        float2 q2 = __half22float2(*(__half2*)&p0.z);
        float2 q3 = __half22float2(*(__half2*)&p0.w);
        *(float4*)&z0s[r][c8]     = make_float4(q0.x, q0.y, q1.x, q1.y);
        *(float4*)&z0s[r][c8 + 4] = make_float4(q2.x, q2.y, q3.x, q3.y);
        q0 = __half22float2(*(__half2*)&p1.x);
        q1 = __half22float2(*(__half2*)&p1.y);
        q2 = __half22float2(*(__half2*)&p1.z);
        q3 = __half22float2(*(__half2*)&p1.w);
        *(float4*)&z1s[r][c8]     = make_float4(q0.x, q0.y, q1.x, q1.y);
        *(float4*)&z1s[r][c8 + 4] = make_float4(q2.x, q2.y, q3.x, q3.y);
    }
    __syncthreads();

    float w0 = wsum[0] * (1.f / N_NODES), w1 = wsum[1] * (1.f / N_NODES);
    float m = fmaxf(w0, w1);
    float e0 = __expf(w0 - m), e1 = __expf(w1 - m);
    float b0 = e0 / (e0 + e1), b1 = 1.f - b0;

    int node = tid >> 3, c = tid & 7;
    float s = bos[c];
    #pragma unroll 8
    for (int k = 0; k < 128; ++k) {
        float hk = b0 * z0s[node][k] + b1 * z1s[node][k];
        s = fmaf(hk, wos[k*8 + c], s);
    }
    out[(n0 + node)*NC + c] = s;
}

// ---------------------------------------------------------------------------
extern "C" void kernel_launch(void* const* d_in, const int* in_sizes, int n_in,
                              void* d_out, int out_size, void* d_ws, size_t ws_size,
                              hipStream_t stream) {
    const float* x     = (const float*)d_in[0];
    const int*   src0  = (const int*)  d_in[1];
    const int*   dst0  = (const int*)  d_in[2];
    const float* ew0   = (const float*)d_in[3];
    const int*   src1  = (const int*)  d_in[4];
    const int*   dst1  = (const int*)  d_in[5];
    const float* ew1   = (const float*)d_in[6];
    const float* Wsrc0 = (const float*)d_in[7];
    const float* Wdst0 = (const float*)d_in[8];
    const float* al0   = (const float*)d_in[9];
    const float* ar0   = (const float*)d_in[10];
    const float* b0    = (const float*)d_in[11];
    const float* Wsrc1 = (const float*)d_in[12];
    const float* Wdst1 = (const float*)d_in[13];
    const float* al1   = (const float*)d_in[14];
    const float* ar1   = (const float*)d_in[15];
    const float* b1    = (const float*)d_in[16];
    const float* Wp1   = (const float*)d_in[17];
    const float* bp1   = (const float*)d_in[18];
    const float* Wp2   = (const float*)d_in[19];
    const float* Wo    = (const float*)d_in[20];
    const float* bo    = (const float*)d_in[21];
    float* out = (float*)d_out;

    // workspace layout (4B units); ~145 MB total, no aliasing
    float*    ws     = (float*)d_ws;
    __half*   FS     = (__half*)ws;                  // 12.8M halves (25.6 MB)
    __half*   ZH0    = (__half*)(ws + 6400000);      // 12.8M halves (25.6 MB)
    __half*   ZH1    = (__half*)(ws + 12800000);     // 12.8M halves (25.6 MB)
    __half*   XH     = (__half*)(ws + 19200000);     // 25.6M halves (51.2 MB)
    float*    ELER   = ws + 32000000;                // 1.6M: EL0,ER0,EL1,ER1 (400k each)
    float*    WF     = ELER + 1600000;               // 4096
    float*    WSUM   = WF + 4096;                    // 8 (pad)
    __half*   WT0    = (__half*)(WSUM + 8);          // 32768 halves = 16384 floats
    __half*   WT1    = (__half*)((float*)WT0 + 16384);
    __half*   WP1T   = (__half*)((float*)WT1 + 16384); // 16384 halves = 8192 floats
    int*      CNT0   = (int*)((float*)WP1T + 8192);  // 100k
    int*      CNT1   = CNT0  + 100000;               // 100k
    unsigned* EDG    = (unsigned*)(CNT1 + 100000);   // 100k*64 = 6.4M (25.6 MB, reused per path)

    hipMemsetAsync(CNT0, 0, sizeof(int)*200000, stream);  // CNT0+CNT1 contiguous
    hipMemsetAsync(WSUM, 0, sizeof(float)*4, stream);

    prep_fold<<<1, 256, 0, stream>>>(Wsrc0, al0, Wdst0, ar0, Wsrc1, al1, Wdst1, ar1, WF);
    prep_tr<<<320, 256, 0, stream>>>(Wsrc0, Wsrc1, Wp1, WT0, WT1, WP1T);
    er_el_kernel<<<N_NODES/16, 256, 0, stream>>>(x, WF, ELER, XH);

    // path 0
    scatter_kernel<<<2048, 256, 0, stream>>>(src0, dst0, ew0, CNT0, EDG);
    gemm_fs_mfma<<<(N_NODES + 63)/64, 256, 0, stream>>>(XH, WT0, FS);
    agg_kernel<<<(N_NODES*64)/256, 256, 0, stream>>>(FS, ELER, ELER + 400000, CNT0, EDG, b0, ZH0);

    // path 1
    scatter_kernel<<<2048, 256, 0, stream>>>(src1, dst1, ew1, CNT1, EDG);
    gemm_fs_mfma<<<(N_NODES + 63)/64, 256, 0, stream>>>(XH, WT1, FS);
    agg_kernel<<<(N_NODES*64)/256, 256, 0, stream>>>(FS, ELER + 800000, ELER + 1200000, CNT1, EDG, b1, ZH1);

    // semantic attention + head
    dim3 semgrid((N_NODES + 63)/64, 2);
    sem_mfma<<<semgrid, 256, 0, stream>>>(ZH0, ZH1, WP1T, bp1, Wp2, WSUM);
    final_kernel<<<N_NODES/32, 256, 0, stream>>>(ZH0, ZH1, Wo, bo, WSUM, out);
}

// Round 6
// 580.067 us; speedup vs baseline: 1.2580x; 1.2580x over previous
//
#include <hip/hip_runtime.h>
#include <hip/hip_fp16.h>
#include <math.h>

#define N_NODES 100000
#define N_EDGES 1600000
#define D_IN    256
#define D_HID   128
#define NH      4
#define NF      32
#define D_SEM   128
#define NC      8
#define NEG_SLOPE 0.2f
#define BUCKET  64          // fixed per-dst edge capacity (max degree ~40 for uniform E/N=16)
#define BIN_SHIFT 9         // 512 nodes per bin
#define BINS    196         // ceil(100000/512)
#define BIN_CAP 9216        // per-bin staging capacity (avg 8192, +5 sigma)
#define CHUNK   8192        // edges per bin_kernel block

typedef _Float16 half8 __attribute__((ext_vector_type(8)));
typedef float    floatx4 __attribute__((ext_vector_type(4)));

struct BinArgs {
    const int*   src[2];
    const int*   dst[2];
    const float* ew[2];
    int*         gcur[2];
    uint2*       binned[2];
};
struct BucketArgs {
    const int*   gcur[2];
    const uint2* binned[2];
    int*         cnt[2];
    unsigned*    edg[2];
};

// ---------------------------------------------------------------------------
// WF[d][p*8 + e*4 + h]:  e=0 -> fold(Wsrc_p, al_p)  (el = x @ WF_el)
//                        e=1 -> fold(Wdst_p, ar_p)  (er = x @ WF_er)
__global__ void prep_fold(const float* __restrict__ Ws0, const float* __restrict__ al0,
                          const float* __restrict__ Wd0, const float* __restrict__ ar0,
                          const float* __restrict__ Ws1, const float* __restrict__ al1,
                          const float* __restrict__ Wd1, const float* __restrict__ ar1,
                          float* __restrict__ WF) {
    int d = threadIdx.x;
    for (int p = 0; p < 2; ++p) {
        const float* Ws = p ? Ws1 : Ws0;
        const float* al = p ? al1 : al0;
        const float* Wd = p ? Wd1 : Wd0;
        const float* ar = p ? ar1 : ar0;
        for (int h = 0; h < NH; ++h) {
            float se = 0.f, sr = 0.f;
            for (int f = 0; f < NF; ++f) {
                se = fmaf(Ws[d*D_HID + h*NF + f], al[h*NF + f], se);
                sr = fmaf(Wd[d*D_HID + h*NF + f], ar[h*NF + f], sr);
            }
            WF[d*16 + p*8 + h]     = se;
            WF[d*16 + p*8 + 4 + h] = sr;
        }
    }
}

// ---------------------------------------------------------------------------
// Pre-transpose + fp16 cast: WT_p[c][k] = Wsrc_p[k][c] (128x256), WP1T[c][k] = Wp1[k][c] (128x128)
__global__ __launch_bounds__(256) void prep_tr(const float* __restrict__ Ws0,
                                               const float* __restrict__ Ws1,
                                               const float* __restrict__ Wp1,
                                               __half* __restrict__ WT0,
                                               __half* __restrict__ WT1,
                                               __half* __restrict__ WP1T) {
    int g = blockIdx.x * 256 + threadIdx.x;
    if (g < 32768) {
        int c = g >> 8, k = g & 255;
        WT0[g] = __float2half_rn(Ws0[k*D_HID + c]);
    } else if (g < 65536) {
        int g2 = g - 32768;
        int c = g2 >> 8, k = g2 & 255;
        WT1[g2] = __float2half_rn(Ws1[k*D_HID + c]);
    } else {
        int g2 = g - 65536;
        int c = g2 >> 7, k = g2 & 127;
        WP1T[g2] = __float2half_rn(Wp1[k*D_SEM + c]);
    }
}

// ---------------------------------------------------------------------------
// One pass over x computing all 16 per-node attention logits, and emitting
// the fp16 copy of x (XH) consumed by both gemm_fs_mfma dispatches.
__global__ __launch_bounds__(256) void er_el_kernel(const float* __restrict__ x,
                                                    const float* __restrict__ WF,
                                                    float* __restrict__ eler,
                                                    __half* __restrict__ XH) {
    __shared__ float xs[16][260];
    __shared__ float wfs[4096];
    int tid = threadIdx.x;
    #pragma unroll
    for (int i = 0; i < 16; ++i) wfs[tid + i*256] = WF[tid + i*256];
    int n0 = blockIdx.x * 16;
    #pragma unroll
    for (int i = 0; i < 4; ++i) {
        int id = tid + i*256;
        int r = id >> 6, c = (id & 63) << 2;
        *(float4*)&xs[r][c] = *(const float4*)&x[(size_t)(n0 + r)*D_IN + c];
    }
    __syncthreads();
    int node = tid >> 4, c = tid & 15;
    float s = 0.f;
    #pragma unroll 8
    for (int k = 0; k < 256; ++k) s = fmaf(xs[node][k], wfs[k*16 + c], s);
    int p = c >> 3, e = (c >> 2) & 1, h = c & 3;
    eler[(p*2 + e)*400000 + (n0 + node)*4 + h] = s;

    #pragma unroll
    for (int i = 0; i < 4; ++i) {
        int id = tid + i*256;
        int r = id >> 6, c4 = (id & 63) << 2;
        float4 v = *(const float4*)&xs[r][c4];
        __half2 h0 = __floats2half2_rn(v.x, v.y);
        __half2 h1 = __floats2half2_rn(v.z, v.w);
        uint2 pk; pk.x = *(unsigned*)&h0; pk.y = *(unsigned*)&h1;
        *(uint2*)&XH[(size_t)(n0 + r)*D_IN + c4] = pk;
    }
}

// ---------------------------------------------------------------------------
// FS = (half)(XH @ W) via v_mfma_f32_16x16x32_f16.  64x128 tile, 4 waves (2x2).
__global__ __launch_bounds__(256) void gemm_fs_mfma(const __half* __restrict__ XH, // [N][256] fp16
                                                    const __half* __restrict__ WT, // [128][256] pre-transposed
                                                    __half* __restrict__ FS) {
    __shared__ unsigned short xs[64][64];    // 8 KB
    __shared__ unsigned short ws[128][64];   // 16 KB (reused as C staging)
    int tid = threadIdx.x;
    int row0 = blockIdx.x * 64;
    int wid = tid >> 6, lane = tid & 63;
    int wm = wid >> 1, wn = wid & 1;
    int lr = lane & 15, lk = lane >> 4;

    floatx4 acc[2][4];
    #pragma unroll
    for (int m = 0; m < 2; ++m)
        #pragma unroll
        for (int n = 0; n < 4; ++n) acc[m][n] = (floatx4){0.f, 0.f, 0.f, 0.f};

    for (int k0 = 0; k0 < D_IN; k0 += 64) {
        #pragma unroll
        for (int i = 0; i < 2; ++i) {
            int id = tid + i*256;
            int r = id >> 3, c8 = (id & 7) << 3;
            int grow = row0 + r;
            uint4 pk = make_uint4(0u, 0u, 0u, 0u);
            if (grow < N_NODES) pk = *(const uint4*)&XH[(size_t)grow*D_IN + k0 + c8];
            int cc = (((c8 >> 3) ^ (r & 7)) << 3);
            *(uint4*)&xs[r][cc] = pk;
        }
        #pragma unroll
        for (int i = 0; i < 8; ++i) {
            int id = tid + i*256;
            int col = id >> 4, c4 = (id & 15) << 2;
            uint2 pk = *(const uint2*)&WT[col*256 + k0 + c4];
            int cc = (((c4 >> 3) ^ (col & 7)) << 3) + (c4 & 7);
            *(uint2*)&ws[col][cc] = pk;
        }
        __syncthreads();
        #pragma unroll
        for (int kk = 0; kk < 2; ++kk) {
            int ksub = kk*4 + lk;
            half8 a[2], b[4];
            #pragma unroll
            for (int m = 0; m < 2; ++m) {
                int r = wm*32 + m*16 + lr;
                a[m] = *(half8*)&xs[r][((ksub ^ (r & 7)) << 3)];
            }
            #pragma unroll
            for (int n = 0; n < 4; ++n) {
                int c = wn*64 + n*16 + lr;
                b[n] = *(half8*)&ws[c][((ksub ^ (c & 7)) << 3)];
            }
            #pragma unroll
            for (int m = 0; m < 2; ++m)
                #pragma unroll
                for (int n = 0; n < 4; ++n)
                    acc[m][n] = __builtin_amdgcn_mfma_f32_16x16x32_f16(a[m], b[n], acc[m][n], 0, 0, 0);
        }
        __syncthreads();
    }

    unsigned short* outs = &ws[0][0];
    #pragma unroll
    for (int m = 0; m < 2; ++m)
        #pragma unroll
        for (int n = 0; n < 4; ++n) {
            int col = wn*64 + n*16 + lr;
            #pragma unroll
            for (int r4 = 0; r4 < 4; ++r4) {
                int rr = wm*32 + m*16 + lk*4 + r4;
                __half hv = __float2half_rn(acc[m][n][r4]);
                outs[rr*128 + col] = *(unsigned short*)&hv;
            }
        }
    __syncthreads();
    #pragma unroll
    for (int i = 0; i < 8; ++i) {
        int id = tid + i*256;
        int r = id >> 5, c4 = (id & 31) << 2;
        int grow = row0 + r;
        if (grow < N_NODES)
            *(uint2*)&FS[(size_t)grow*D_HID + c4] = *(uint2*)&outs[r*128 + c4];
    }
}

// ---------------------------------------------------------------------------
// Pass A: partition edges into 196 dst-bins with coalesced run writes.
// blockIdx.y selects the meta-path (fused mode) — both paths in one dispatch.
__global__ __launch_bounds__(1024) void bin_kernel(BinArgs A) {
    __shared__ uint2 stage[CHUNK];            // 64 KB
    __shared__ unsigned char binof[CHUNK];    // 8 KB
    __shared__ int bcnt[256], boff[256], gbase[256], brun[256];
    int P = blockIdx.y;
    const int*   src = A.src[P];
    const int*   dst = A.dst[P];
    const float* ew  = A.ew[P];
    int*         gcur = A.gcur[P];
    uint2*       binned = A.binned[P];

    int tid = threadIdx.x;
    int c0 = blockIdx.x * CHUNK;
    int C = N_EDGES - c0; if (C > CHUNK) C = CHUNK;
    if (C <= 0) return;

    if (tid < 256) bcnt[tid] = 0;
    __syncthreads();
    for (int j = tid; j < C; j += 1024)
        atomicAdd(&bcnt[dst[c0 + j] >> BIN_SHIFT], 1);
    __syncthreads();

    int v = (tid < 256) ? bcnt[tid] : 0;
    if (tid < 256) boff[tid] = v;
    __syncthreads();
    for (int o = 1; o < 256; o <<= 1) {       // inclusive Hillis-Steele
        int u = (tid < 256 && tid >= o) ? boff[tid - o] : 0;
        __syncthreads();
        if (tid < 256) boff[tid] += u;
        __syncthreads();
    }
    if (tid < 256) {
        boff[tid] -= v;                       // exclusive
        brun[tid] = 0;
        if (tid < BINS) gbase[tid] = v ? atomicAdd(&gcur[tid], v) : 0;
    }
    __syncthreads();

    for (int j = tid; j < C; j += 1024) {
        int e = c0 + j;
        int d = dst[e];
        int b = d >> BIN_SHIFT;
        unsigned q = (unsigned)(ew[e] * 32767.f + 0.5f);
        int p = atomicAdd(&brun[b], 1);
        int sl = boff[b] + p;
        stage[sl] = make_uint2(((unsigned)src[e] << 15) | q, (unsigned)d);
        binof[sl] = (unsigned char)b;
    }
    __syncthreads();

    for (int j = tid; j < C; j += 1024) {     // coalesced run copy-out
        int b = binof[j];
        int off = gbase[b] + (j - boff[b]);
        if (off < BIN_CAP) binned[b * BIN_CAP + off] = stage[j];
    }
}

// ---------------------------------------------------------------------------
// Pass B: sub-bin blocks — block nb handles nodes [nb*256, nb*256+256) of bin
// nb>>1 (64 KB LDS -> 2 blocks/CU; 392 x npaths blocks). Streams out only
// used slots; writes per-node cnt (no memset needed).
__global__ __launch_bounds__(1024) void bucket_kernel(BucketArgs A) {
    __shared__ unsigned buck[256 * BUCKET];   // 64 KB
    __shared__ int lcnt[256];
    int P = blockIdx.y;
    const int*   gcur   = A.gcur[P];
    const uint2* binned = A.binned[P];
    int*         cnt    = A.cnt[P];
    unsigned*    edg    = A.edg[P];

    int tid = threadIdx.x;
    int nb = blockIdx.x;          // sub-bin index, 0..391
    int b  = nb >> 1;             // parent bin
    int n0 = nb << 8;             // first node of sub-bin
    int lo = (nb & 1) << 8;       // dl window [lo, lo+256) within bin
    if (tid < 256) lcnt[tid] = 0;
    __syncthreads();

    int cE = gcur[b]; if (cE > BIN_CAP) cE = BIN_CAP;
    int bn0 = b << BIN_SHIFT;
    for (int j = tid; j < cE; j += 1024) {
        uint2 r = binned[b * BIN_CAP + j];
        int w = ((int)r.y - bn0) - lo;        // in-window offset
        if ((unsigned)w < 256u) {
            int p = atomicAdd(&lcnt[w], 1);
            if (p < BUCKET) buck[(w << 6) + p] = r.x;
        }
    }
    __syncthreads();

    const uint4* b4 = (const uint4*)buck;
    uint4* e4 = (uint4*)edg;
    for (int i = tid; i < 256 * BUCKET / 4; i += 1024) {
        int node = n0 + (i >> 4);             // 16 uint4 per node
        int used = lcnt[i >> 4];
        if (node < N_NODES && ((i & 15) << 2) < used)
            e4[((size_t)node << 4) + (i & 15)] = b4[i];
    }
    if (tid < 256) {
        int node = n0 + tid;
        if (node < N_NODES) cnt[node] = lcnt[tid] < BUCKET ? lcnt[tid] : BUCKET;
    }
}

// ---------------------------------------------------------------------------
// Atomic-free aggregation, 16-edge super-iterations (R3-proven form):
//  - 64 lanes compute 64 DISTINCT (edge,head) coefficients per phase;
//  - redistribution via 2 shuffles per consumed edge;
//  - 4 independent predicated FS gathers in flight; f16 z output.
__global__ __launch_bounds__(256) void agg_kernel(const __half* __restrict__ FS,
                                                  const float* __restrict__ el,
                                                  const float* __restrict__ er,
                                                  const int* __restrict__ cnt,
                                                  const unsigned* __restrict__ edg,
                                                  const float* __restrict__ bias,
                                                  __half* __restrict__ zh) {
    int wv = (blockIdx.x * 256 + threadIdx.x) >> 6;
    int lane = threadIdx.x & 63;
    if (wv >= N_NODES) return;
    int q  = lane >> 4;          // edge slot 0..3
    int ql = lane & 15;          // covers feats [8ql, 8ql+8)
    int hh = lane & 3;           // head for the coefficient this lane computes
    float erh = er[wv*4 + hh];
    int cn = cnt[wv];
    if (cn > BUCKET) cn = BUCKET;
    int beg = wv << 6;
    const __half* fsq = FS + (ql << 3);

    float4 a0 = make_float4(0.f,0.f,0.f,0.f);
    float4 a1 = make_float4(0.f,0.f,0.f,0.f);

    int nIt = (cn + 15) >> 4;
    for (int it = 0; it < nIt; ++it) {
        int jb = it << 4;
        int sl = jb + (lane >> 2);            // edge slot this lane covers
        int slc = sl < cn ? sl : cn - 1;      // clamp (cn>=1 when loop entered)
        unsigned w = edg[beg + slc];
        int s = (int)(w >> 15);
        float a = (float)(w & 32767u) * (1.f / 32767.f);
        float v = el[s*4 + hh] + erh;
        v = v > 0.f ? v : NEG_SLOPE * v;
        a = a * __builtin_amdgcn_rcpf(1.f + __expf(-v));
        a = sl < cn ? a : 0.f;
        #pragma unroll
        for (int u = 0; u < 4; ++u) {
            int e = (u << 2) + q;
            int su = jb + e;
            int ssrc = __shfl(s, e << 2);
            uint4 raw = make_uint4(0u, 0u, 0u, 0u);
            if (su < cn) raw = *(const uint4*)&fsq[(size_t)ssrc * D_HID];
            float av = __shfl(a, (e << 2) | (ql >> 2));
            float2 f0 = __half22float2(*(__half2*)&raw.x);
            float2 f1 = __half22float2(*(__half2*)&raw.y);
            float2 f2 = __half22float2(*(__half2*)&raw.z);
            float2 f3 = __half22float2(*(__half2*)&raw.w);
            a0.x = fmaf(f0.x, av, a0.x); a0.y = fmaf(f0.y, av, a0.y);
            a0.z = fmaf(f1.x, av, a0.z); a0.w = fmaf(f1.y, av, a0.w);
            a1.x = fmaf(f2.x, av, a1.x); a1.y = fmaf(f2.y, av, a1.y);
            a1.z = fmaf(f3.x, av, a1.z); a1.w = fmaf(f3.y, av, a1.w);
        }
    }

    #pragma unroll
    for (int o = 16; o < 64; o <<= 1) {
        a0.x += __shfl_xor(a0.x, o); a0.y += __shfl_xor(a0.y, o);
        a0.z += __shfl_xor(a0.z, o); a0.w += __shfl_xor(a0.w, o);
        a1.x += __shfl_xor(a1.x, o); a1.y += __shfl_xor(a1.y, o);
        a1.z += __shfl_xor(a1.z, o); a1.w += __shfl_xor(a1.w, o);
    }

    if (q < 2) {
        int c = (ql << 3) + (q << 2);
        float4 r = q ? a1 : a0;
        float4 bv = *(const float4*)&bias[c];
        r.x += bv.x; r.y += bv.y; r.z += bv.z; r.w += bv.w;
        r.x = r.x > 0.f ? r.x : expm1f(r.x);
        r.y = r.y > 0.f ? r.y : expm1f(r.y);
        r.z = r.z > 0.f ? r.z : expm1f(r.z);
        r.w = r.w > 0.f ? r.w : expm1f(r.w);
        __half2 h0 = __floats2half2_rn(r.x, r.y);
        __half2 h1 = __floats2half2_rn(r.z, r.w);
        uint2 pk; pk.x = *(unsigned*)&h0; pk.y = *(unsigned*)&h1;
        *(uint2*)&zh[(size_t)wv*D_HID + c] = pk;
    }
}

// ---------------------------------------------------------------------------
// Semantic attention scores via MFMA; one atomicAdd per block into wsum[path].
__global__ __launch_bounds__(256) void sem_mfma(const __half* __restrict__ zh0,
                                                const __half* __restrict__ zh1,
                                                const __half* __restrict__ WP1T,
                                                const float* __restrict__ bp1,
                                                const float* __restrict__ Wp2,
                                                float* __restrict__ wsum) {
    __shared__ unsigned short zs[64][128];    // 16 KB
    __shared__ unsigned short ps[128][128];   // 32 KB
    __shared__ float red[4];
    const __half* z = blockIdx.y ? zh1 : zh0;
    int tid = threadIdx.x;
    int row0 = blockIdx.x * 64;
    int wid = tid >> 6, lane = tid & 63;
    int wm = wid >> 1, wn = wid & 1;
    int lr = lane & 15, lk = lane >> 4;

    #pragma unroll
    for (int i = 0; i < 4; ++i) {
        int id = tid + i*256;
        int r = id >> 4, ch = id & 15;
        int grow = row0 + r;
        uint4 pk = make_uint4(0u, 0u, 0u, 0u);
        if (grow < N_NODES) pk = *(const uint4*)&z[(size_t)grow*D_HID + (ch << 3)];
        *(uint4*)&zs[r][((ch ^ (r & 7)) << 3)] = pk;
    }
    #pragma unroll
    for (int i = 0; i < 16; ++i) {
        int id = tid + i*256;
        int c = id >> 5, k4 = (id & 31) << 2;
        uint2 pk = *(const uint2*)&WP1T[c*128 + k4];
        int cc = (((k4 >> 3) ^ (c & 7)) << 3) + (k4 & 7);
        *(uint2*)&ps[c][cc] = pk;
    }
    __syncthreads();

    floatx4 acc[2][4];
    #pragma unroll
    for (int m = 0; m < 2; ++m)
        #pragma unroll
        for (int n = 0; n < 4; ++n) acc[m][n] = (floatx4){0.f, 0.f, 0.f, 0.f};

    #pragma unroll
    for (int kk = 0; kk < 4; ++kk) {
        int ksub = kk*4 + lk;
        half8 a[2], b[4];
        #pragma unroll
        for (int m = 0; m < 2; ++m) {
            int r = wm*32 + m*16 + lr;
            a[m] = *(half8*)&zs[r][((ksub ^ (r & 7)) << 3)];
        }
        #pragma unroll
        for (int n = 0; n < 4; ++n) {
            int c = wn*64 + n*16 + lr;
            b[n] = *(half8*)&ps[c][((ksub ^ (c & 7)) << 3)];
        }
        #pragma unroll
        for (int m = 0; m < 2; ++m)
            #pragma unroll
            for (int n = 0; n < 4; ++n)
                acc[m][n] = __builtin_amdgcn_mfma_f32_16x16x32_f16(a[m], b[n], acc[m][n], 0, 0, 0);
    }

    float s = 0.f;
    #pragma unroll
    for (int m = 0; m < 2; ++m)
        #pragma unroll
        for (int n = 0; n < 4; ++n) {
            int col = wn*64 + n*16 + lr;
            float bp = bp1[col];
            float w2 = Wp2[col];
            #pragma unroll
            for (int r4 = 0; r4 < 4; ++r4) {
                int grow = row0 + wm*32 + m*16 + lk*4 + r4;
                if (grow < N_NODES) {
                    float v = acc[m][n][r4] + bp;
                    float t = 1.f - 2.f / (__expf(2.f*v) + 1.f);
                    s = fmaf(t, w2, s);
                }
            }
        }
    #pragma unroll
    for (int o = 1; o < 64; o <<= 1) s += __shfl_xor(s, o);
    if (lane == 0) red[wid] = s;
    __syncthreads();
    if (tid == 0) atomicAdd(&wsum[blockIdx.y], red[0] + red[1] + red[2] + red[3]);
}

// ---------------------------------------------------------------------------
// out[n,c] = bo[c] + sum_k (b0*z0[n,k] + b1*z1[n,k]) * Wo[k,c]; z inputs f16.
__global__ __launch_bounds__(256) void final_kernel(const __half* __restrict__ zh0,
                                                    const __half* __restrict__ zh1,
                                                    const float* __restrict__ Wo,
                                                    const float* __restrict__ bo,
                                                    const float* __restrict__ wsum,
                                                    float* __restrict__ out) {
    __shared__ float z0s[32][132];
    __shared__ float z1s[32][132];
    __shared__ float wos[128*8];
    __shared__ float bos[8];
    int tid = threadIdx.x;
    int n0 = blockIdx.x * 32;
    #pragma unroll
    for (int i = 0; i < 4; ++i) wos[tid + i*256] = Wo[tid + i*256];
    if (tid < 8) bos[tid] = bo[tid];
    #pragma unroll
    for (int i = 0; i < 2; ++i) {
        int id = tid + i*256;
        int r = id >> 4, c8 = (id & 15) << 3;
        uint4 p0 = *(const uint4*)&zh0[(size_t)(n0 + r)*D_HID + c8];
        uint4 p1 = *(const uint4*)&zh1[(size_t)(n0 + r)*D_HID + c8];
        float2 q0 = __half22float2(*(__half2*)&p0.x);
        float2 q1 = __half22float2(*(__half2*)&p0.y);
        float2 q2 = __half22float2(*(__half2*)&p0.z);
        float2 q3 = __half22float2(*(__half2*)&p0.w);
        *(float4*)&z0s[r][c8]     = make_float4(q0.x, q0.y, q1.x, q1.y);
        *(float4*)&z0s[r][c8 + 4] = make_float4(q2.x, q2.y, q3.x, q3.y);
        q0 = __half22float2(*(__half2*)&p1.x);
        q1 = __half22float2(*(__half2*)&p1.y);
        q2 = __half22float2(*(__half2*)&p1.z);
        q3 = __half22float2(*(__half2*)&p1.w);
        *(float4*)&z1s[r][c8]     = make_float4(q0.x, q0.y, q1.x, q1.y);
        *(float4*)&z1s[r][c8 + 4] = make_float4(q2.x, q2.y, q3.x, q3.y);
    }
    __syncthreads();

    float w0 = wsum[0] * (1.f / N_NODES), w1 = wsum[1] * (1.f / N_NODES);
    float m = fmaxf(w0, w1);
    float e0 = __expf(w0 - m), e1 = __expf(w1 - m);
    float b0 = e0 / (e0 + e1), b1 = 1.f - b0;

    int node = tid >> 3, c = tid & 7;
    float s = bos[c];
    #pragma unroll 8
    for (int k = 0; k < 128; ++k) {
        float hk = b0 * z0s[node][k] + b1 * z1s[node][k];
        s = fmaf(hk, wos[k*8 + c], s);
    }
    out[(n0 + node)*NC + c] = s;
}

// ---------------------------------------------------------------------------
extern "C" void kernel_launch(void* const* d_in, const int* in_sizes, int n_in,
                              void* d_out, int out_size, void* d_ws, size_t ws_size,
                              hipStream_t stream) {
    const float* x     = (const float*)d_in[0];
    const int*   src0  = (const int*)  d_in[1];
    const int*   dst0  = (const int*)  d_in[2];
    const float* ew0   = (const float*)d_in[3];
    const int*   src1  = (const int*)  d_in[4];
    const int*   dst1  = (const int*)  d_in[5];
    const float* ew1   = (const float*)d_in[6];
    const float* Wsrc0 = (const float*)d_in[7];
    const float* Wdst0 = (const float*)d_in[8];
    const float* al0   = (const float*)d_in[9];
    const float* ar0   = (const float*)d_in[10];
    const float* b0    = (const float*)d_in[11];
    const float* Wsrc1 = (const float*)d_in[12];
    const float* Wdst1 = (const float*)d_in[13];
    const float* al1   = (const float*)d_in[14];
    const float* ar1   = (const float*)d_in[15];
    const float* b1    = (const float*)d_in[16];
    const float* Wp1   = (const float*)d_in[17];
    const float* bp1   = (const float*)d_in[18];
    const float* Wp2   = (const float*)d_in[19];
    const float* Wo    = (const float*)d_in[20];
    const float* bo    = (const float*)d_in[21];
    float* out = (float*)d_out;

    // ---- workspace layout (4B units). Base (serial) = 175.4 MB; fused adds
    //      a second EDG+BINNED (+40 MB -> 215.5 MB) enabling single-dispatch
    //      dual-path bin/bucket. Runtime branch on ws_size keeps both safe.
    float*    ws     = (float*)d_ws;
    __half*   FS     = (__half*)ws;                    // 25.6 MB
    __half*   ZH0    = (__half*)(ws + 6400000);        // 25.6 MB
    __half*   ZH1    = (__half*)(ws + 12800000);       // 25.6 MB
    __half*   XH     = (__half*)(ws + 19200000);       // 51.2 MB
    float*    ELER   = ws + 32000000;                  // 6.4 MB
    float*    WF     = ELER + 1600000;
    float*    WSUM   = WF + 4096;
    __half*   WT0    = (__half*)(WSUM + 8);
    __half*   WT1    = (__half*)((float*)WT0 + 16384);
    __half*   WP1T   = (__half*)((float*)WT1 + 16384);
    int*      CNT0   = (int*)((float*)WP1T + 8192);
    int*      CNT1   = CNT0  + 100000;
    int*      GCUR0  = CNT1  + 100000;                 // 256
    int*      GCUR1  = GCUR0 + 256;                    // 256
    unsigned* EDG0   = (unsigned*)(GCUR1 + 256);       // 25.6 MB
    uint2*    BINNED0= (uint2*)(EDG0 + 6400000);       // 14.45 MB
    float*    endser = (float*)BINNED0 + 2*(size_t)BINS*BIN_CAP;
    unsigned* EDG1   = (unsigned*)endser;              // fused only: 25.6 MB
    uint2*    BINNED1= (uint2*)(EDG1 + 6400000);       // fused only: 14.45 MB
    size_t fused_bytes = (size_t)((float*)BINNED1 + 2*(size_t)BINS*BIN_CAP - ws) * 4;
    bool fused = ws_size >= fused_bytes;
    if (!fused) { EDG1 = EDG0; BINNED1 = BINNED0; }

    hipMemsetAsync(GCUR0, 0, sizeof(int)*512, stream);   // GCUR0+GCUR1 contiguous
    hipMemsetAsync(WSUM, 0, sizeof(float)*4, stream);

    prep_fold<<<1, 256, 0, stream>>>(Wsrc0, al0, Wdst0, ar0, Wsrc1, al1, Wdst1, ar1, WF);
    prep_tr<<<320, 256, 0, stream>>>(Wsrc0, Wsrc1, Wp1, WT0, WT1, WP1T);
    er_el_kernel<<<N_NODES/16, 256, 0, stream>>>(x, WF, ELER, XH);

    int nchunks = (N_EDGES + CHUNK - 1) / CHUNK;   // 196
    if (fused) {
        BinArgs ba = {{src0, src1}, {dst0, dst1}, {ew0, ew1},
                      {GCUR0, GCUR1}, {BINNED0, BINNED1}};
        bin_kernel<<<dim3(nchunks, 2), 1024, 0, stream>>>(ba);
        BucketArgs ka = {{GCUR0, GCUR1}, {BINNED0, BINNED1},
                         {CNT0, CNT1}, {EDG0, EDG1}};
        bucket_kernel<<<dim3(2*BINS, 2), 1024, 0, stream>>>(ka);
        gemm_fs_mfma<<<(N_NODES + 63)/64, 256, 0, stream>>>(XH, WT0, FS);
        agg_kernel<<<(N_NODES*64)/256, 256, 0, stream>>>(FS, ELER, ELER + 400000, CNT0, EDG0, b0, ZH0);
        gemm_fs_mfma<<<(N_NODES + 63)/64, 256, 0, stream>>>(XH, WT1, FS);
        agg_kernel<<<(N_NODES*64)/256, 256, 0, stream>>>(FS, ELER + 800000, ELER + 1200000, CNT1, EDG1, b1, ZH1);
    } else {
        BinArgs ba0 = {{src0, src0}, {dst0, dst0}, {ew0, ew0},
                       {GCUR0, GCUR0}, {BINNED0, BINNED0}};
        BucketArgs ka0 = {{GCUR0, GCUR0}, {BINNED0, BINNED0},
                          {CNT0, CNT0}, {EDG0, EDG0}};
        bin_kernel<<<dim3(nchunks, 1), 1024, 0, stream>>>(ba0);
        bucket_kernel<<<dim3(2*BINS, 1), 1024, 0, stream>>>(ka0);
        gemm_fs_mfma<<<(N_NODES + 63)/64, 256, 0, stream>>>(XH, WT0, FS);
        agg_kernel<<<(N_NODES*64)/256, 256, 0, stream>>>(FS, ELER, ELER + 400000, CNT0, EDG0, b0, ZH0);
        BinArgs ba1 = {{src1, src1}, {dst1, dst1}, {ew1, ew1},
                       {GCUR1, GCUR1}, {BINNED0, BINNED0}};
        BucketArgs ka1 = {{GCUR1, GCUR1}, {BINNED0, BINNED0},
                          {CNT1, CNT1}, {EDG0, EDG0}};
        bin_kernel<<<dim3(nchunks, 1), 1024, 0, stream>>>(ba1);
        bucket_kernel<<<dim3(2*BINS, 1), 1024, 0, stream>>>(ka1);
        gemm_fs_mfma<<<(N_NODES + 63)/64, 256, 0, stream>>>(XH, WT1, FS);
        agg_kernel<<<(N_NODES*64)/256, 256, 0, stream>>>(FS, ELER + 800000, ELER + 1200000, CNT1, EDG0, b1, ZH1);
    }

    // semantic attention + head
    dim3 semgrid((N_NODES + 63)/64, 2);
    sem_mfma<<<semgrid, 256, 0, stream>>>(ZH0, ZH1, WP1T, bp1, Wp2, WSUM);
    final_kernel<<<N_NODES/32, 256, 0, stream>>>(ZH0, ZH1, Wo, bo, WSUM, out);
}

// Round 7
// 549.849 us; speedup vs baseline: 1.3272x; 1.0550x over previous
//
#include <hip/hip_runtime.h>
#include <hip/hip_fp16.h>
#include <math.h>

#define N_NODES 100000
#define N_EDGES 1600000
#define D_IN    256
#define D_HID   128
#define NH      4
#define NF      32
#define D_SEM   128
#define NC      8
#define NEG_SLOPE 0.2f
#define BUCKET  64          // fixed per-dst edge capacity (max degree ~40 for uniform E/N=16)
#define BIN_SHIFT 9         // 512 nodes per bin
#define BINS    196         // ceil(100000/512)
#define BIN_CAP 9216        // per-bin staging capacity (avg 8192, +5 sigma)
#define CHUNK   8192        // edges per bin_kernel block

typedef _Float16 half8 __attribute__((ext_vector_type(8)));
typedef float    floatx4 __attribute__((ext_vector_type(4)));

struct BinArgs {
    const int*   src[2];
    const int*   dst[2];
    const float* ew[2];
    int*         gcur[2];
    uint2*       binned[2];
};
struct BucketArgs {
    const int*   gcur[2];
    const uint2* binned[2];
    int*         cnt[2];
    unsigned*    edg[2];
};

// ---------------------------------------------------------------------------
// WTA[col][k], 272 cols x 256 k (f16):
//   cols 0-127   = Wsrc0^T            (FS0 = XH @ cols)
//   cols 128-255 = Wsrc1^T            (FS1)
//   cols 256-263 = fold(Wdst_p, ar_p) (er:  col 256+p*4+h)
//   cols 264-271 = 0 (pad)
// Also WP1T[c][k] = Wp1[k][c] f16 (128x128).
__global__ __launch_bounds__(256) void prep(const float* __restrict__ Ws0,
                                            const float* __restrict__ Ws1,
                                            const float* __restrict__ Wd0,
                                            const float* __restrict__ ar0,
                                            const float* __restrict__ Wd1,
                                            const float* __restrict__ ar1,
                                            const float* __restrict__ Wp1,
                                            __half* __restrict__ WTA,
                                            __half* __restrict__ WP1T) {
    int g = blockIdx.x * 256 + threadIdx.x;
    if (g < 32768) {
        int col = g >> 8, k = g & 255;
        WTA[(size_t)col*256 + k] = __float2half_rn(Ws0[k*D_HID + col]);
    } else if (g < 65536) {
        int g2 = g - 32768;
        int col = g2 >> 8, k = g2 & 255;
        WTA[(size_t)(128 + col)*256 + k] = __float2half_rn(Ws1[k*D_HID + col]);
    } else if (g < 69632) {
        int g2 = g - 65536;                 // 0..4095
        int j = g2 >> 8, k = g2 & 255;      // j = 0..15
        float s = 0.f;
        if (j < 8) {
            int p = j >> 2, h = j & 3;
            const float* Wd = p ? Wd1 : Wd0;
            const float* ar = p ? ar1 : ar0;
            for (int f = 0; f < NF; ++f)
                s = fmaf(Wd[k*D_HID + h*NF + f], ar[h*NF + f], s);
        }
        WTA[(size_t)(256 + j)*256 + k] = __float2half_rn(s);
    } else if (g < 86016) {
        int g2 = g - 69632;                 // 0..16383
        int c = g2 >> 7, k = g2 & 127;
        WP1T[g2] = __float2half_rn(Wp1[k*D_SEM + c]);
    }
}

// ---------------------------------------------------------------------------
// One x pass producing FS0, FS1 (f16) and all 16 per-node logits (el via
// al-weighted epilogue on acc; er via the extra 16-col MFMA fragment).
// 64 rows/block, 4 waves: wave wid covers cols wid*64..wid*64+63 of [FS0|FS1];
// wave 0 additionally computes cols 256-271 (er block).
__global__ __launch_bounds__(256) void fs_all(const float* __restrict__ x,
                                              const __half* __restrict__ WTA, // [272][256]
                                              const float* __restrict__ al0,
                                              const float* __restrict__ al1,
                                              __half* __restrict__ FS0,
                                              __half* __restrict__ FS1,
                                              float* __restrict__ eler) {
    __shared__ unsigned short xs[64][256];   // 32 KB (reused as C staging)
    __shared__ unsigned short wsB[272][64];  // 34 KB
    int tid = threadIdx.x;
    int row0 = blockIdx.x * 64;
    int wid = tid >> 6, lane = tid & 63;
    int lr = lane & 15, lk = lane >> 4;

    // stage x: 64 rows x 256 halves, f32 -> f16, XOR-swizzled by 8-half chunk
    #pragma unroll
    for (int i = 0; i < 8; ++i) {
        int id = tid + i*256;                // 2048 items
        int r = id >> 5, c8 = (id & 31) << 3;
        int grow = row0 + r;
        float4 v0 = make_float4(0.f,0.f,0.f,0.f), v1 = v0;
        if (grow < N_NODES) {
            v0 = *(const float4*)&x[(size_t)grow*D_IN + c8];
            v1 = *(const float4*)&x[(size_t)grow*D_IN + c8 + 4];
        }
        __half2 h0 = __floats2half2_rn(v0.x, v0.y);
        __half2 h1 = __floats2half2_rn(v0.z, v0.w);
        __half2 h2 = __floats2half2_rn(v1.x, v1.y);
        __half2 h3 = __floats2half2_rn(v1.z, v1.w);
        uint4 pk;
        pk.x = *(unsigned*)&h0; pk.y = *(unsigned*)&h1;
        pk.z = *(unsigned*)&h2; pk.w = *(unsigned*)&h3;
        int ch = c8 >> 3;                    // 0..31
        *(uint4*)&xs[r][((ch ^ (r & 7)) << 3)] = pk;
    }

    floatx4 acc[4][4];
    floatx4 acc4[4];
    #pragma unroll
    for (int m = 0; m < 4; ++m) {
        acc4[m] = (floatx4){0.f, 0.f, 0.f, 0.f};
        #pragma unroll
        for (int n = 0; n < 4; ++n) acc[m][n] = (floatx4){0.f, 0.f, 0.f, 0.f};
    }

    for (int kc = 0; kc < 4; ++kc) {
        // stage W chunk: 272 cols x 64 halves (4352 uint2 items / 17 per thread)
        #pragma unroll
        for (int i = 0; i < 17; ++i) {
            int id = tid + i*256;
            int col = id >> 4, c4 = (id & 15) << 2;
            uint2 pk = *(const uint2*)&WTA[(size_t)col*256 + kc*64 + c4];
            int cc = (((c4 >> 3) ^ (col & 7)) << 3) + (c4 & 7);
            *(uint2*)&wsB[col][cc] = pk;
        }
        __syncthreads();
        #pragma unroll
        for (int kk = 0; kk < 2; ++kk) {
            int kl = kk*4 + lk;              // local chunk 0..7
            int kg = kc*8 + kl;              // global chunk 0..31
            half8 a[4], b[5];
            #pragma unroll
            for (int m = 0; m < 4; ++m) {
                int r = m*16 + lr;
                a[m] = *(half8*)&xs[r][((kg ^ (r & 7)) << 3)];
            }
            #pragma unroll
            for (int n = 0; n < 4; ++n) {
                int c = wid*64 + n*16 + lr;
                b[n] = *(half8*)&wsB[c][((kl ^ (c & 7)) << 3)];
            }
            if (wid == 0) {
                int c = 256 + lr;
                b[4] = *(half8*)&wsB[c][((kl ^ (c & 7)) << 3)];
            }
            #pragma unroll
            for (int m = 0; m < 4; ++m)
                #pragma unroll
                for (int n = 0; n < 4; ++n)
                    acc[m][n] = __builtin_amdgcn_mfma_f32_16x16x32_f16(a[m], b[n], acc[m][n], 0, 0, 0);
            if (wid == 0) {
                #pragma unroll
                for (int m = 0; m < 4; ++m)
                    acc4[m] = __builtin_amdgcn_mfma_f32_16x16x32_f16(a[m], b[4], acc4[m], 0, 0, 0);
            }
        }
        __syncthreads();
    }

    // ---- el epilogue: wave wid covers heads {2*(wid&1), +1} of path wid>>1
    {
        int p = wid >> 1;
        const float* al = p ? al1 : al0;
        int h0 = (wid & 1) * 2;
        float av00 = al[h0*NF + lr],     av01 = al[h0*NF + 16 + lr];
        float av10 = al[(h0+1)*NF + lr], av11 = al[(h0+1)*NF + 16 + lr];
        #pragma unroll
        for (int m = 0; m < 4; ++m)
            #pragma unroll
            for (int r4 = 0; r4 < 4; ++r4) {
                float s0 = acc[m][0][r4]*av00 + acc[m][1][r4]*av01;
                float s1 = acc[m][2][r4]*av10 + acc[m][3][r4]*av11;
                #pragma unroll
                for (int o = 1; o < 16; o <<= 1) {
                    s0 += __shfl_xor(s0, o);
                    s1 += __shfl_xor(s1, o);
                }
                int row = row0 + m*16 + lk*4 + r4;
                if (lr == 0 && row < N_NODES) {
                    eler[(p*2)*400000 + row*4 + h0]     = s0;
                    eler[(p*2)*400000 + row*4 + h0 + 1] = s1;
                }
            }
    }
    // ---- er epilogue (wave 0, lanes lr<8): col 256+lr -> path lr>>2, head lr&3
    if (wid == 0 && lr < 8) {
        int p = lr >> 2, h = lr & 3;
        #pragma unroll
        for (int m = 0; m < 4; ++m)
            #pragma unroll
            for (int r4 = 0; r4 < 4; ++r4) {
                int row = row0 + m*16 + lk*4 + r4;
                if (row < N_NODES)
                    eler[(p*2+1)*400000 + row*4 + h] = acc4[m][r4];
            }
    }

    // ---- C store: stage to LDS (reuse xs: 64 rows x 256 cols), coalesced out
    __syncthreads();
    #pragma unroll
    for (int n = 0; n < 4; ++n) {
        int col = wid*64 + n*16 + lr;
        #pragma unroll
        for (int m = 0; m < 4; ++m)
            #pragma unroll
            for (int r4 = 0; r4 < 4; ++r4) {
                int rr = m*16 + lk*4 + r4;
                __half hv = __float2half_rn(acc[m][n][r4]);
                xs[rr][col] = *(unsigned short*)&hv;
            }
    }
    __syncthreads();
    #pragma unroll
    for (int i = 0; i < 8; ++i) {
        int id = tid + i*256;
        int r = id >> 5, c8 = (id & 31) << 3;
        int grow = row0 + r;
        if (grow < N_NODES) {
            uint4 pk = *(uint4*)&xs[r][c8];
            if (c8 < 128) *(uint4*)&FS0[(size_t)grow*D_HID + c8]       = pk;
            else          *(uint4*)&FS1[(size_t)grow*D_HID + c8 - 128] = pk;
        }
    }
}

// ---------------------------------------------------------------------------
// Pass A: partition edges into 196 dst-bins with coalesced run writes.
// blockIdx.y selects the meta-path (fused mode) — both paths in one dispatch.
__global__ __launch_bounds__(1024) void bin_kernel(BinArgs A) {
    __shared__ uint2 stage[CHUNK];            // 64 KB
    __shared__ unsigned char binof[CHUNK];    // 8 KB
    __shared__ int bcnt[256], boff[256], gbase[256], brun[256];
    int P = blockIdx.y;
    const int*   src = A.src[P];
    const int*   dst = A.dst[P];
    const float* ew  = A.ew[P];
    int*         gcur = A.gcur[P];
    uint2*       binned = A.binned[P];

    int tid = threadIdx.x;
    int c0 = blockIdx.x * CHUNK;
    int C = N_EDGES - c0; if (C > CHUNK) C = CHUNK;
    if (C <= 0) return;

    if (tid < 256) bcnt[tid] = 0;
    __syncthreads();
    for (int j = tid; j < C; j += 1024)
        atomicAdd(&bcnt[dst[c0 + j] >> BIN_SHIFT], 1);
    __syncthreads();

    int v = (tid < 256) ? bcnt[tid] : 0;
    if (tid < 256) boff[tid] = v;
    __syncthreads();
    for (int o = 1; o < 256; o <<= 1) {       // inclusive Hillis-Steele
        int u = (tid < 256 && tid >= o) ? boff[tid - o] : 0;
        __syncthreads();
        if (tid < 256) boff[tid] += u;
        __syncthreads();
    }
    if (tid < 256) {
        boff[tid] -= v;                       // exclusive
        brun[tid] = 0;
        if (tid < BINS) gbase[tid] = v ? atomicAdd(&gcur[tid], v) : 0;
    }
    __syncthreads();

    for (int j = tid; j < C; j += 1024) {
        int e = c0 + j;
        int d = dst[e];
        int b = d >> BIN_SHIFT;
        unsigned q = (unsigned)(ew[e] * 32767.f + 0.5f);
        int p = atomicAdd(&brun[b], 1);
        int sl = boff[b] + p;
        stage[sl] = make_uint2(((unsigned)src[e] << 15) | q, (unsigned)d);
        binof[sl] = (unsigned char)b;
    }
    __syncthreads();

    for (int j = tid; j < C; j += 1024) {     // coalesced run copy-out
        int b = binof[j];
        int off = gbase[b] + (j - boff[b]);
        if (off < BIN_CAP) binned[b * BIN_CAP + off] = stage[j];
    }
}

// ---------------------------------------------------------------------------
// Pass B: sub-bin blocks — block nb handles nodes [nb*256, nb*256+256) of bin
// nb>>1 (64 KB LDS -> 2 blocks/CU). Streams out only used slots.
__global__ __launch_bounds__(1024) void bucket_kernel(BucketArgs A) {
    __shared__ unsigned buck[256 * BUCKET];   // 64 KB
    __shared__ int lcnt[256];
    int P = blockIdx.y;
    const int*   gcur   = A.gcur[P];
    const uint2* binned = A.binned[P];
    int*         cnt    = A.cnt[P];
    unsigned*    edg    = A.edg[P];

    int tid = threadIdx.x;
    int nb = blockIdx.x;          // sub-bin index, 0..391
    int b  = nb >> 1;             // parent bin
    int n0 = nb << 8;             // first node of sub-bin
    int lo = (nb & 1) << 8;       // dl window [lo, lo+256) within bin
    if (tid < 256) lcnt[tid] = 0;
    __syncthreads();

    int cE = gcur[b]; if (cE > BIN_CAP) cE = BIN_CAP;
    int bn0 = b << BIN_SHIFT;
    for (int j = tid; j < cE; j += 1024) {
        uint2 r = binned[b * BIN_CAP + j];
        int w = ((int)r.y - bn0) - lo;        // in-window offset
        if ((unsigned)w < 256u) {
            int p = atomicAdd(&lcnt[w], 1);
            if (p < BUCKET) buck[(w << 6) + p] = r.x;
        }
    }
    __syncthreads();

    const uint4* b4 = (const uint4*)buck;
    uint4* e4 = (uint4*)edg;
    for (int i = tid; i < 256 * BUCKET / 4; i += 1024) {
        int node = n0 + (i >> 4);             // 16 uint4 per node
        int used = lcnt[i >> 4];
        if (node < N_NODES && ((i & 15) << 2) < used)
            e4[((size_t)node << 4) + (i & 15)] = b4[i];
    }
    if (tid < 256) {
        int node = n0 + tid;
        if (node < N_NODES) cnt[node] = lcnt[tid] < BUCKET ? lcnt[tid] : BUCKET;
    }
}

// ---------------------------------------------------------------------------
// Atomic-free aggregation, 16-edge super-iterations (R3/R6-proven form).
__global__ __launch_bounds__(256) void agg_kernel(const __half* __restrict__ FS,
                                                  const float* __restrict__ el,
                                                  const float* __restrict__ er,
                                                  const int* __restrict__ cnt,
                                                  const unsigned* __restrict__ edg,
                                                  const float* __restrict__ bias,
                                                  __half* __restrict__ zh) {
    int wv = (blockIdx.x * 256 + threadIdx.x) >> 6;
    int lane = threadIdx.x & 63;
    if (wv >= N_NODES) return;
    int q  = lane >> 4;          // edge slot 0..3
    int ql = lane & 15;          // covers feats [8ql, 8ql+8)
    int hh = lane & 3;           // head for the coefficient this lane computes
    float erh = er[wv*4 + hh];
    int cn = cnt[wv];
    if (cn > BUCKET) cn = BUCKET;
    int beg = wv << 6;
    const __half* fsq = FS + (ql << 3);

    float4 a0 = make_float4(0.f,0.f,0.f,0.f);
    float4 a1 = make_float4(0.f,0.f,0.f,0.f);

    int nIt = (cn + 15) >> 4;
    for (int it = 0; it < nIt; ++it) {
        int jb = it << 4;
        int sl = jb + (lane >> 2);            // edge slot this lane covers
        int slc = sl < cn ? sl : cn - 1;      // clamp (cn>=1 when loop entered)
        unsigned w = edg[beg + slc];
        int s = (int)(w >> 15);
        float a = (float)(w & 32767u) * (1.f / 32767.f);
        float v = el[s*4 + hh] + erh;
        v = v > 0.f ? v : NEG_SLOPE * v;
        a = a * __builtin_amdgcn_rcpf(1.f + __expf(-v));
        a = sl < cn ? a : 0.f;
        #pragma unroll
        for (int u = 0; u < 4; ++u) {
            int e = (u << 2) + q;
            int su = jb + e;
            int ssrc = __shfl(s, e << 2);
            uint4 raw = make_uint4(0u, 0u, 0u, 0u);
            if (su < cn) raw = *(const uint4*)&fsq[(size_t)ssrc * D_HID];
            float av = __shfl(a, (e << 2) | (ql >> 2));
            float2 f0 = __half22float2(*(__half2*)&raw.x);
            float2 f1 = __half22float2(*(__half2*)&raw.y);
            float2 f2 = __half22float2(*(__half2*)&raw.z);
            float2 f3 = __half22float2(*(__half2*)&raw.w);
            a0.x = fmaf(f0.x, av, a0.x); a0.y = fmaf(f0.y, av, a0.y);
            a0.z = fmaf(f1.x, av, a0.z); a0.w = fmaf(f1.y, av, a0.w);
            a1.x = fmaf(f2.x, av, a1.x); a1.y = fmaf(f2.y, av, a1.y);
            a1.z = fmaf(f3.x, av, a1.z); a1.w = fmaf(f3.y, av, a1.w);
        }
    }

    #pragma unroll
    for (int o = 16; o < 64; o <<= 1) {
        a0.x += __shfl_xor(a0.x, o); a0.y += __shfl_xor(a0.y, o);
        a0.z += __shfl_xor(a0.z, o); a0.w += __shfl_xor(a0.w, o);
        a1.x += __shfl_xor(a1.x, o); a1.y += __shfl_xor(a1.y, o);
        a1.z += __shfl_xor(a1.z, o); a1.w += __shfl_xor(a1.w, o);
    }

    if (q < 2) {
        int c = (ql << 3) + (q << 2);
        float4 r = q ? a1 : a0;
        float4 bv = *(const float4*)&bias[c];
        r.x += bv.x; r.y += bv.y; r.z += bv.z; r.w += bv.w;
        r.x = r.x > 0.f ? r.x : expm1f(r.x);
        r.y = r.y > 0.f ? r.y : expm1f(r.y);
        r.z = r.z > 0.f ? r.z : expm1f(r.z);
        r.w = r.w > 0.f ? r.w : expm1f(r.w);
        __half2 h0 = __floats2half2_rn(r.x, r.y);
        __half2 h1 = __floats2half2_rn(r.z, r.w);
        uint2 pk; pk.x = *(unsigned*)&h0; pk.y = *(unsigned*)&h1;
        *(uint2*)&zh[(size_t)wv*D_HID + c] = pk;
    }
}

// ---------------------------------------------------------------------------
// Semantic attention scores via MFMA; one atomicAdd per block into wsum[path].
__global__ __launch_bounds__(256) void sem_mfma(const __half* __restrict__ zh0,
                                                const __half* __restrict__ zh1,
                                                const __half* __restrict__ WP1T,
                                                const float* __restrict__ bp1,
                                                const float* __restrict__ Wp2,
                                                float* __restrict__ wsum) {
    __shared__ unsigned short zs[64][128];    // 16 KB
    __shared__ unsigned short ps[128][128];   // 32 KB
    __shared__ float red[4];
    const __half* z = blockIdx.y ? zh1 : zh0;
    int tid = threadIdx.x;
    int row0 = blockIdx.x * 64;
    int wid = tid >> 6, lane = tid & 63;
    int wm = wid >> 1, wn = wid & 1;
    int lr = lane & 15, lk = lane >> 4;

    #pragma unroll
    for (int i = 0; i < 4; ++i) {
        int id = tid + i*256;
        int r = id >> 4, ch = id & 15;
        int grow = row0 + r;
        uint4 pk = make_uint4(0u, 0u, 0u, 0u);
        if (grow < N_NODES) pk = *(const uint4*)&z[(size_t)grow*D_HID + (ch << 3)];
        *(uint4*)&zs[r][((ch ^ (r & 7)) << 3)] = pk;
    }
    #pragma unroll
    for (int i = 0; i < 16; ++i) {
        int id = tid + i*256;
        int c = id >> 5, k4 = (id & 31) << 2;
        uint2 pk = *(const uint2*)&WP1T[c*128 + k4];
        int cc = (((k4 >> 3) ^ (c & 7)) << 3) + (k4 & 7);
        *(uint2*)&ps[c][cc] = pk;
    }
    __syncthreads();

    floatx4 acc[2][4];
    #pragma unroll
    for (int m = 0; m < 2; ++m)
        #pragma unroll
        for (int n = 0; n < 4; ++n) acc[m][n] = (floatx4){0.f, 0.f, 0.f, 0.f};

    #pragma unroll
    for (int kk = 0; kk < 4; ++kk) {
        int ksub = kk*4 + lk;
        half8 a[2], b[4];
        #pragma unroll
        for (int m = 0; m < 2; ++m) {
            int r = wm*32 + m*16 + lr;
            a[m] = *(half8*)&zs[r][((ksub ^ (r & 7)) << 3)];
        }
        #pragma unroll
        for (int n = 0; n < 4; ++n) {
            int c = wn*64 + n*16 + lr;
            b[n] = *(half8*)&ps[c][((ksub ^ (c & 7)) << 3)];
        }
        #pragma unroll
        for (int m = 0; m < 2; ++m)
            #pragma unroll
            for (int n = 0; n < 4; ++n)
                acc[m][n] = __builtin_amdgcn_mfma_f32_16x16x32_f16(a[m], b[n], acc[m][n], 0, 0, 0);
    }

    float s = 0.f;
    #pragma unroll
    for (int m = 0; m < 2; ++m)
        #pragma unroll
        for (int n = 0; n < 4; ++n) {
            int col = wn*64 + n*16 + lr;
            float bp = bp1[col];
            float w2 = Wp2[col];
            #pragma unroll
            for (int r4 = 0; r4 < 4; ++r4) {
                int grow = row0 + wm*32 + m*16 + lk*4 + r4;
                if (grow < N_NODES) {
                    float v = acc[m][n][r4] + bp;
                    float t = 1.f - 2.f / (__expf(2.f*v) + 1.f);
                    s = fmaf(t, w2, s);
                }
            }
        }
    #pragma unroll
    for (int o = 1; o < 64; o <<= 1) s += __shfl_xor(s, o);
    if (lane == 0) red[wid] = s;
    __syncthreads();
    if (tid == 0) atomicAdd(&wsum[blockIdx.y], red[0] + red[1] + red[2] + red[3]);
}

// ---------------------------------------------------------------------------
// out[n,c] = bo[c] + sum_k (b0*z0[n,k] + b1*z1[n,k]) * Wo[k,c]; z inputs f16.
__global__ __launch_bounds__(256) void final_kernel(const __half* __restrict__ zh0,
                                                    const __half* __restrict__ zh1,
                                                    const float* __restrict__ Wo,
                                                    const float* __restrict__ bo,
                                                    const float* __restrict__ wsum,
                                                    float* __restrict__ out) {
    __shared__ float z0s[32][132];
    __shared__ float z1s[32][132];
    __shared__ float wos[128*8];
    __shared__ float bos[8];
    int tid = threadIdx.x;
    int n0 = blockIdx.x * 32;
    #pragma unroll
    for (int i = 0; i < 4; ++i) wos[tid + i*256] = Wo[tid + i*256];
    if (tid < 8) bos[tid] = bo[tid];
    #pragma unroll
    for (int i = 0; i < 2; ++i) {
        int id = tid + i*256;
        int r = id >> 4, c8 = (id & 15) << 3;
        uint4 p0 = *(const uint4*)&zh0[(size_t)(n0 + r)*D_HID + c8];
        uint4 p1 = *(const uint4*)&zh1[(size_t)(n0 + r)*D_HID + c8];
        float2 q0 = __half22float2(*(__half2*)&p0.x);
        float2 q1 = __half22float2(*(__half2*)&p0.y);
        float2 q2 = __half22float2(*(__half2*)&p0.z);
        float2 q3 = __half22float2(*(__half2*)&p0.w);
        *(float4*)&z0s[r][c8]     = make_float4(q0.x, q0.y, q1.x, q1.y);
        *(float4*)&z0s[r][c8 + 4] = make_float4(q2.x, q2.y, q3.x, q3.y);
        q0 = __half22float2(*(__half2*)&p1.x);
        q1 = __half22float2(*(__half2*)&p1.y);
        q2 = __half22float2(*(__half2*)&p1.z);
        q3 = __half22float2(*(__half2*)&p1.w);
        *(float4*)&z1s[r][c8]     = make_float4(q0.x, q0.y, q1.x, q1.y);
        *(float4*)&z1s[r][c8 + 4] = make_float4(q2.x, q2.y, q3.x, q3.y);
    }
    __syncthreads();

    float w0 = wsum[0] * (1.f / N_NODES), w1 = wsum[1] * (1.f / N_NODES);
    float m = fmaxf(w0, w1);
    float e0 = __expf(w0 - m), e1 = __expf(w1 - m);
    float b0 = e0 / (e0 + e1), b1 = 1.f - b0;

    int node = tid >> 3, c = tid & 7;
    float s = bos[c];
    #pragma unroll 8
    for (int k = 0; k < 128; ++k) {
        float hk = b0 * z0s[node][k] + b1 * z1s[node][k];
        s = fmaf(hk, wos[k*8 + c], s);
    }
    out[(n0 + node)*NC + c] = s;
}

// ---------------------------------------------------------------------------
extern "C" void kernel_launch(void* const* d_in, const int* in_sizes, int n_in,
                              void* d_out, int out_size, void* d_ws, size_t ws_size,
                              hipStream_t stream) {
    const float* x     = (const float*)d_in[0];
    const int*   src0  = (const int*)  d_in[1];
    const int*   dst0  = (const int*)  d_in[2];
    const float* ew0   = (const float*)d_in[3];
    const int*   src1  = (const int*)  d_in[4];
    const int*   dst1  = (const int*)  d_in[5];
    const float* ew1   = (const float*)d_in[6];
    const float* Wsrc0 = (const float*)d_in[7];
    const float* Wdst0 = (const float*)d_in[8];
    const float* al0   = (const float*)d_in[9];
    const float* ar0   = (const float*)d_in[10];
    const float* b0    = (const float*)d_in[11];
    const float* Wsrc1 = (const float*)d_in[12];
    const float* Wdst1 = (const float*)d_in[13];
    const float* al1   = (const float*)d_in[14];
    const float* ar1   = (const float*)d_in[15];
    const float* b1    = (const float*)d_in[16];
    const float* Wp1   = (const float*)d_in[17];
    const float* bp1   = (const float*)d_in[18];
    const float* Wp2   = (const float*)d_in[19];
    const float* Wo    = (const float*)d_in[20];
    const float* bo    = (const float*)d_in[21];
    float* out = (float*)d_out;

    // ---- workspace layout (4B float units). Serial = ~150 MB; fused adds a
    //      second EDG+BINNED (+40 MB -> ~190 MB). Runtime branch on ws_size.
    float*    ws     = (float*)d_ws;
    __half*   FS0    = (__half*)ws;                    // 25.6 MB
    __half*   FS1    = (__half*)(ws + 6400000);        // 25.6 MB
    __half*   ZH0    = (__half*)(ws + 12800000);       // 25.6 MB
    __half*   ZH1    = (__half*)(ws + 19200000);       // 25.6 MB
    float*    ELER   = ws + 25600000;                  // 6.4 MB
    float*    WSUM   = ELER + 1600000;                 // 8
    __half*   WTA    = (__half*)(WSUM + 8);            // 272*256 halves = 34816 floats
    __half*   WP1T   = (__half*)((float*)WTA + 34816); // 16384 halves = 8192 floats
    int*      CNT0   = (int*)((float*)WP1T + 8192);    // 100k
    int*      CNT1   = CNT0  + 100000;                 // 100k
    int*      GCUR0  = CNT1  + 100000;                 // 256
    int*      GCUR1  = GCUR0 + 256;                    // 256
    unsigned* EDG0   = (unsigned*)(GCUR1 + 256);       // 25.6 MB
    uint2*    BINNED0= (uint2*)(EDG0 + 6400000);       // 14.45 MB
    float*    endser = (float*)BINNED0 + 2*(size_t)BINS*BIN_CAP;
    unsigned* EDG1   = (unsigned*)endser;              // fused only: 25.6 MB
    uint2*    BINNED1= (uint2*)(EDG1 + 6400000);       // fused only: 14.45 MB
    size_t fused_bytes = (size_t)((float*)BINNED1 + 2*(size_t)BINS*BIN_CAP - ws) * 4;
    bool fused = ws_size >= fused_bytes;
    if (!fused) { EDG1 = EDG0; BINNED1 = BINNED0; }

    hipMemsetAsync(GCUR0, 0, sizeof(int)*512, stream);   // GCUR0+GCUR1 contiguous
    hipMemsetAsync(WSUM, 0, sizeof(float)*4, stream);

    prep<<<336, 256, 0, stream>>>(Wsrc0, Wsrc1, Wdst0, ar0, Wdst1, ar1, Wp1, WTA, WP1T);
    fs_all<<<(N_NODES + 63)/64, 256, 0, stream>>>(x, WTA, al0, al1, FS0, FS1, ELER);

    int nchunks = (N_EDGES + CHUNK - 1) / CHUNK;   // 196
    if (fused) {
        BinArgs ba = {{src0, src1}, {dst0, dst1}, {ew0, ew1},
                      {GCUR0, GCUR1}, {BINNED0, BINNED1}};
        bin_kernel<<<dim3(nchunks, 2), 1024, 0, stream>>>(ba);
        BucketArgs ka = {{GCUR0, GCUR1}, {BINNED0, BINNED1},
                         {CNT0, CNT1}, {EDG0, EDG1}};
        bucket_kernel<<<dim3(2*BINS, 2), 1024, 0, stream>>>(ka);
        agg_kernel<<<(N_NODES*64)/256, 256, 0, stream>>>(FS0, ELER, ELER + 400000, CNT0, EDG0, b0, ZH0);
        agg_kernel<<<(N_NODES*64)/256, 256, 0, stream>>>(FS1, ELER + 800000, ELER + 1200000, CNT1, EDG1, b1, ZH1);
    } else {
        BinArgs ba0 = {{src0, src0}, {dst0, dst0}, {ew0, ew0},
                       {GCUR0, GCUR0}, {BINNED0, BINNED0}};
        BucketArgs ka0 = {{GCUR0, GCUR0}, {BINNED0, BINNED0},
                          {CNT0, CNT0}, {EDG0, EDG0}};
        bin_kernel<<<dim3(nchunks, 1), 1024, 0, stream>>>(ba0);
        bucket_kernel<<<dim3(2*BINS, 1), 1024, 0, stream>>>(ka0);
        agg_kernel<<<(N_NODES*64)/256, 256, 0, stream>>>(FS0, ELER, ELER + 400000, CNT0, EDG0, b0, ZH0);
        BinArgs ba1 = {{src1, src1}, {dst1, dst1}, {ew1, ew1},
                       {GCUR1, GCUR1}, {BINNED0, BINNED0}};
        BucketArgs ka1 = {{GCUR1, GCUR1}, {BINNED0, BINNED0},
                          {CNT1, CNT1}, {EDG0, EDG0}};
        bin_kernel<<<dim3(nchunks, 1), 1024, 0, stream>>>(ba1);
        bucket_kernel<<<dim3(2*BINS, 1), 1024, 0, stream>>>(ka1);
        agg_kernel<<<(N_NODES*64)/256, 256, 0, stream>>>(FS1, ELER + 800000, ELER + 1200000, CNT1, EDG0, b1, ZH1);
    }

    // semantic attention + head
    dim3 semgrid((N_NODES + 63)/64, 2);
    sem_mfma<<<semgrid, 256, 0, stream>>>(ZH0, ZH1, WP1T, bp1, Wp2, WSUM);
    final_kernel<<<N_NODES/32, 256, 0, stream>>>(ZH0, ZH1, Wo, bo, WSUM, out);
}

// Round 8
// 518.316 us; speedup vs baseline: 1.4079x; 1.0608x over previous
//
#include <hip/hip_runtime.h>
#include <hip/hip_fp16.h>
#include <math.h>

#define N_NODES 100000
#define N_EDGES 1600000
#define D_IN    256
#define D_HID   128
#define NH      4
#define NF      32
#define D_SEM   128
#define NC      8
#define NEG_SLOPE 0.2f
#define BUCKET  64          // fixed per-dst edge capacity (max degree ~40 for uniform E/N=16)
#define BIN_SHIFT 9         // 512 nodes per bin
#define BINS    196         // ceil(100000/512)
#define BIN_CAP 9216        // per-bin staging capacity (avg 8192, +5 sigma)
#define CHUNK   8192        // edges per bin_kernel block

typedef _Float16 half8 __attribute__((ext_vector_type(8)));
typedef float    floatx4 __attribute__((ext_vector_type(4)));

struct BinArgs {
    const int*   src[2];
    const int*   dst[2];
    const float* ew[2];
    int*         gcur[2];
    uint2*       binned[2];
};
struct BucketArgs {
    const int*   gcur[2];
    const uint2* binned[2];
    int*         cnt[2];
    unsigned*    edg[2];
};

// ---------------------------------------------------------------------------
// WTA[col][k], 272 cols x 256 k (f16):
//   cols 0-127   = Wsrc0^T            (FS0 = XH @ cols)
//   cols 128-255 = Wsrc1^T            (FS1)
//   cols 256-263 = fold(Wdst_p, ar_p) (er:  col 256+p*4+h)
//   cols 264-271 = 0 (pad)
// Also WP1T[c][k] = Wp1[k][c] f16 (128x128).
__global__ __launch_bounds__(256) void prep(const float* __restrict__ Ws0,
                                            const float* __restrict__ Ws1,
                                            const float* __restrict__ Wd0,
                                            const float* __restrict__ ar0,
                                            const float* __restrict__ Wd1,
                                            const float* __restrict__ ar1,
                                            const float* __restrict__ Wp1,
                                            __half* __restrict__ WTA,
                                            __half* __restrict__ WP1T) {
    int g = blockIdx.x * 256 + threadIdx.x;
    if (g < 32768) {
        int col = g >> 8, k = g & 255;
        WTA[(size_t)col*256 + k] = __float2half_rn(Ws0[k*D_HID + col]);
    } else if (g < 65536) {
        int g2 = g - 32768;
        int col = g2 >> 8, k = g2 & 255;
        WTA[(size_t)(128 + col)*256 + k] = __float2half_rn(Ws1[k*D_HID + col]);
    } else if (g < 69632) {
        int g2 = g - 65536;                 // 0..4095
        int j = g2 >> 8, k = g2 & 255;      // j = 0..15
        float s = 0.f;
        if (j < 8) {
            int p = j >> 2, h = j & 3;
            const float* Wd = p ? Wd1 : Wd0;
            const float* ar = p ? ar1 : ar0;
            for (int f = 0; f < NF; ++f)
                s = fmaf(Wd[k*D_HID + h*NF + f], ar[h*NF + f], s);
        }
        WTA[(size_t)(256 + j)*256 + k] = __float2half_rn(s);
    } else if (g < 86016) {
        int g2 = g - 69632;                 // 0..16383
        int c = g2 >> 7, k = g2 & 127;
        WP1T[g2] = __float2half_rn(Wp1[k*D_SEM + c]);
    }
}

// ---------------------------------------------------------------------------
// One x pass producing FS0, FS1 (f16) and all 16 per-node logits (el via
// al-weighted epilogue on acc; er via the extra 16-col MFMA fragment).
// 32 rows/block (xs 16 KB + wsB 34 KB = 50 KB -> 3 blocks/CU, 12 waves),
// 4 waves: wave wid covers cols wid*64..wid*64+63 of [FS0|FS1]; wave 0
// additionally computes cols 256-271 (er block).
__global__ __launch_bounds__(256) void fs_all(const float* __restrict__ x,
                                              const __half* __restrict__ WTA, // [272][256]
                                              const float* __restrict__ al0,
                                              const float* __restrict__ al1,
                                              __half* __restrict__ FS0,
                                              __half* __restrict__ FS1,
                                              float* __restrict__ eler) {
    __shared__ unsigned short xs[32][256];   // 16 KB (reused as C staging)
    __shared__ unsigned short wsB[272][64];  // 34 KB
    int tid = threadIdx.x;
    int row0 = blockIdx.x * 32;
    int wid = tid >> 6, lane = tid & 63;
    int lr = lane & 15, lk = lane >> 4;

    // stage x: 32 rows x 256 halves, f32 -> f16, XOR-swizzled by 8-half chunk
    #pragma unroll
    for (int i = 0; i < 4; ++i) {
        int id = tid + i*256;                // 1024 items
        int r = id >> 5, c8 = (id & 31) << 3;
        int grow = row0 + r;
        float4 v0 = make_float4(0.f,0.f,0.f,0.f), v1 = v0;
        if (grow < N_NODES) {
            v0 = *(const float4*)&x[(size_t)grow*D_IN + c8];
            v1 = *(const float4*)&x[(size_t)grow*D_IN + c8 + 4];
        }
        __half2 h0 = __floats2half2_rn(v0.x, v0.y);
        __half2 h1 = __floats2half2_rn(v0.z, v0.w);
        __half2 h2 = __floats2half2_rn(v1.x, v1.y);
        __half2 h3 = __floats2half2_rn(v1.z, v1.w);
        uint4 pk;
        pk.x = *(unsigned*)&h0; pk.y = *(unsigned*)&h1;
        pk.z = *(unsigned*)&h2; pk.w = *(unsigned*)&h3;
        int ch = c8 >> 3;                    // 0..31
        *(uint4*)&xs[r][((ch ^ (r & 7)) << 3)] = pk;
    }

    floatx4 acc[2][4];
    floatx4 acc4[2];
    #pragma unroll
    for (int m = 0; m < 2; ++m) {
        acc4[m] = (floatx4){0.f, 0.f, 0.f, 0.f};
        #pragma unroll
        for (int n = 0; n < 4; ++n) acc[m][n] = (floatx4){0.f, 0.f, 0.f, 0.f};
    }

    for (int kc = 0; kc < 4; ++kc) {
        // stage W chunk: 272 cols x 64 halves (4352 uint2 items / 17 per thread)
        #pragma unroll
        for (int i = 0; i < 17; ++i) {
            int id = tid + i*256;
            int col = id >> 4, c4 = (id & 15) << 2;
            uint2 pk = *(const uint2*)&WTA[(size_t)col*256 + kc*64 + c4];
            int cc = (((c4 >> 3) ^ (col & 7)) << 3) + (c4 & 7);
            *(uint2*)&wsB[col][cc] = pk;
        }
        __syncthreads();
        #pragma unroll
        for (int kk = 0; kk < 2; ++kk) {
            int kl = kk*4 + lk;              // local chunk 0..7
            int kg = kc*8 + kl;              // global chunk 0..31
            half8 a[2], b[5];
            #pragma unroll
            for (int m = 0; m < 2; ++m) {
                int r = m*16 + lr;
                a[m] = *(half8*)&xs[r][((kg ^ (r & 7)) << 3)];
            }
            #pragma unroll
            for (int n = 0; n < 4; ++n) {
                int c = wid*64 + n*16 + lr;
                b[n] = *(half8*)&wsB[c][((kl ^ (c & 7)) << 3)];
            }
            if (wid == 0) {
                int c = 256 + lr;
                b[4] = *(half8*)&wsB[c][((kl ^ (c & 7)) << 3)];
            }
            #pragma unroll
            for (int m = 0; m < 2; ++m)
                #pragma unroll
                for (int n = 0; n < 4; ++n)
                    acc[m][n] = __builtin_amdgcn_mfma_f32_16x16x32_f16(a[m], b[n], acc[m][n], 0, 0, 0);
            if (wid == 0) {
                #pragma unroll
                for (int m = 0; m < 2; ++m)
                    acc4[m] = __builtin_amdgcn_mfma_f32_16x16x32_f16(a[m], b[4], acc4[m], 0, 0, 0);
            }
        }
        __syncthreads();
    }

    // ---- el epilogue: wave wid covers heads {2*(wid&1), +1} of path wid>>1
    {
        int p = wid >> 1;
        const float* al = p ? al1 : al0;
        int h0 = (wid & 1) * 2;
        float av00 = al[h0*NF + lr],     av01 = al[h0*NF + 16 + lr];
        float av10 = al[(h0+1)*NF + lr], av11 = al[(h0+1)*NF + 16 + lr];
        #pragma unroll
        for (int m = 0; m < 2; ++m)
            #pragma unroll
            for (int r4 = 0; r4 < 4; ++r4) {
                float s0 = acc[m][0][r4]*av00 + acc[m][1][r4]*av01;
                float s1 = acc[m][2][r4]*av10 + acc[m][3][r4]*av11;
                #pragma unroll
                for (int o = 1; o < 16; o <<= 1) {
                    s0 += __shfl_xor(s0, o);
                    s1 += __shfl_xor(s1, o);
                }
                int row = row0 + m*16 + lk*4 + r4;
                if (lr == 0 && row < N_NODES) {
                    eler[(p*2)*400000 + row*4 + h0]     = s0;
                    eler[(p*2)*400000 + row*4 + h0 + 1] = s1;
                }
            }
    }
    // ---- er epilogue (wave 0, lanes lr<8): col 256+lr -> path lr>>2, head lr&3
    if (wid == 0 && lr < 8) {
        int p = lr >> 2, h = lr & 3;
        #pragma unroll
        for (int m = 0; m < 2; ++m)
            #pragma unroll
            for (int r4 = 0; r4 < 4; ++r4) {
                int row = row0 + m*16 + lk*4 + r4;
                if (row < N_NODES)
                    eler[(p*2+1)*400000 + row*4 + h] = acc4[m][r4];
            }
    }

    // ---- C store: stage to LDS (reuse xs: 32 rows x 256 cols), coalesced out
    __syncthreads();
    #pragma unroll
    for (int n = 0; n < 4; ++n) {
        int col = wid*64 + n*16 + lr;
        #pragma unroll
        for (int m = 0; m < 2; ++m)
            #pragma unroll
            for (int r4 = 0; r4 < 4; ++r4) {
                int rr = m*16 + lk*4 + r4;
                __half hv = __float2half_rn(acc[m][n][r4]);
                xs[rr][col] = *(unsigned short*)&hv;
            }
    }
    __syncthreads();
    #pragma unroll
    for (int i = 0; i < 4; ++i) {
        int id = tid + i*256;
        int r = id >> 5, c8 = (id & 31) << 3;
        int grow = row0 + r;
        if (grow < N_NODES) {
            uint4 pk = *(uint4*)&xs[r][c8];
            if (c8 < 128) *(uint4*)&FS0[(size_t)grow*D_HID + c8]       = pk;
            else          *(uint4*)&FS1[(size_t)grow*D_HID + c8 - 128] = pk;
        }
    }
}

// ---------------------------------------------------------------------------
// Pass A: partition edges into 196 dst-bins with coalesced run writes.
// blockIdx.y selects the meta-path (fused mode) — both paths in one dispatch.
__global__ __launch_bounds__(1024) void bin_kernel(BinArgs A) {
    __shared__ uint2 stage[CHUNK];            // 64 KB
    __shared__ unsigned char binof[CHUNK];    // 8 KB
    __shared__ int bcnt[256], boff[256], gbase[256], brun[256];
    int P = blockIdx.y;
    const int*   src = A.src[P];
    const int*   dst = A.dst[P];
    const float* ew  = A.ew[P];
    int*         gcur = A.gcur[P];
    uint2*       binned = A.binned[P];

    int tid = threadIdx.x;
    int c0 = blockIdx.x * CHUNK;
    int C = N_EDGES - c0; if (C > CHUNK) C = CHUNK;
    if (C <= 0) return;

    if (tid < 256) bcnt[tid] = 0;
    __syncthreads();
    for (int j = tid; j < C; j += 1024)
        atomicAdd(&bcnt[dst[c0 + j] >> BIN_SHIFT], 1);
    __syncthreads();

    int v = (tid < 256) ? bcnt[tid] : 0;
    if (tid < 256) boff[tid] = v;
    __syncthreads();
    for (int o = 1; o < 256; o <<= 1) {       // inclusive Hillis-Steele
        int u = (tid < 256 && tid >= o) ? boff[tid - o] : 0;
        __syncthreads();
        if (tid < 256) boff[tid] += u;
        __syncthreads();
    }
    if (tid < 256) {
        boff[tid] -= v;                       // exclusive
        brun[tid] = 0;
        if (tid < BINS) gbase[tid] = v ? atomicAdd(&gcur[tid], v) : 0;
    }
    __syncthreads();

    for (int j = tid; j < C; j += 1024) {
        int e = c0 + j;
        int d = dst[e];
        int b = d >> BIN_SHIFT;
        unsigned q = (unsigned)(ew[e] * 32767.f + 0.5f);
        int p = atomicAdd(&brun[b], 1);
        int sl = boff[b] + p;
        stage[sl] = make_uint2(((unsigned)src[e] << 15) | q, (unsigned)d);
        binof[sl] = (unsigned char)b;
    }
    __syncthreads();

    for (int j = tid; j < C; j += 1024) {     // coalesced run copy-out
        int b = binof[j];
        int off = gbase[b] + (j - boff[b]);
        if (off < BIN_CAP) binned[b * BIN_CAP + off] = stage[j];
    }
}

// ---------------------------------------------------------------------------
// Pass B: sub-bin blocks — block nb handles nodes [nb*256, nb*256+256) of bin
// nb>>1 (64 KB LDS -> 2 blocks/CU). Streams out only used slots.
__global__ __launch_bounds__(1024) void bucket_kernel(BucketArgs A) {
    __shared__ unsigned buck[256 * BUCKET];   // 64 KB
    __shared__ int lcnt[256];
    int P = blockIdx.y;
    const int*   gcur   = A.gcur[P];
    const uint2* binned = A.binned[P];
    int*         cnt    = A.cnt[P];
    unsigned*    edg    = A.edg[P];

    int tid = threadIdx.x;
    int nb = blockIdx.x;          // sub-bin index, 0..391
    int b  = nb >> 1;             // parent bin
    int n0 = nb << 8;             // first node of sub-bin
    int lo = (nb & 1) << 8;       // dl window [lo, lo+256) within bin
    if (tid < 256) lcnt[tid] = 0;
    __syncthreads();

    int cE = gcur[b]; if (cE > BIN_CAP) cE = BIN_CAP;
    int bn0 = b << BIN_SHIFT;
    for (int j = tid; j < cE; j += 1024) {
        uint2 r = binned[b * BIN_CAP + j];
        int w = ((int)r.y - bn0) - lo;        // in-window offset
        if ((unsigned)w < 256u) {
            int p = atomicAdd(&lcnt[w], 1);
            if (p < BUCKET) buck[(w << 6) + p] = r.x;
        }
    }
    __syncthreads();

    const uint4* b4 = (const uint4*)buck;
    uint4* e4 = (uint4*)edg;
    for (int i = tid; i < 256 * BUCKET / 4; i += 1024) {
        int node = n0 + (i >> 4);             // 16 uint4 per node
        int used = lcnt[i >> 4];
        if (node < N_NODES && ((i & 15) << 2) < used)
            e4[((size_t)node << 4) + (i & 15)] = b4[i];
    }
    if (tid < 256) {
        int node = n0 + tid;
        if (node < N_NODES) cnt[node] = lcnt[tid] < BUCKET ? lcnt[tid] : BUCKET;
    }
}

// ---------------------------------------------------------------------------
// Atomic-free aggregation, 16-edge super-iterations (R3/R6-proven form).
__global__ __launch_bounds__(256) void agg_kernel(const __half* __restrict__ FS,
                                                  const float* __restrict__ el,
                                                  const float* __restrict__ er,
                                                  const int* __restrict__ cnt,
                                                  const unsigned* __restrict__ edg,
                                                  const float* __restrict__ bias,
                                                  __half* __restrict__ zh) {
    int wv = (blockIdx.x * 256 + threadIdx.x) >> 6;
    int lane = threadIdx.x & 63;
    if (wv >= N_NODES) return;
    int q  = lane >> 4;          // edge slot 0..3
    int ql = lane & 15;          // covers feats [8ql, 8ql+8)
    int hh = lane & 3;           // head for the coefficient this lane computes
    float erh = er[wv*4 + hh];
    int cn = cnt[wv];
    if (cn > BUCKET) cn = BUCKET;
    int beg = wv << 6;
    const __half* fsq = FS + (ql << 3);

    float4 a0 = make_float4(0.f,0.f,0.f,0.f);
    float4 a1 = make_float4(0.f,0.f,0.f,0.f);

    int nIt = (cn + 15) >> 4;
    for (int it = 0; it < nIt; ++it) {
        int jb = it << 4;
        int sl = jb + (lane >> 2);            // edge slot this lane covers
        int slc = sl < cn ? sl : cn - 1;      // clamp (cn>=1 when loop entered)
        unsigned w = edg[beg + slc];
        int s = (int)(w >> 15);
        float a = (float)(w & 32767u) * (1.f / 32767.f);
        float v = el[s*4 + hh] + erh;
        v = v > 0.f ? v : NEG_SLOPE * v;
        a = a * __builtin_amdgcn_rcpf(1.f + __expf(-v));
        a = sl < cn ? a : 0.f;
        #pragma unroll
        for (int u = 0; u < 4; ++u) {
            int e = (u << 2) + q;
            int su = jb + e;
            int ssrc = __shfl(s, e << 2);
            uint4 raw = make_uint4(0u, 0u, 0u, 0u);
            if (su < cn) raw = *(const uint4*)&fsq[(size_t)ssrc * D_HID];
            float av = __shfl(a, (e << 2) | (ql >> 2));
            float2 f0 = __half22float2(*(__half2*)&raw.x);
            float2 f1 = __half22float2(*(__half2*)&raw.y);
            float2 f2 = __half22float2(*(__half2*)&raw.z);
            float2 f3 = __half22float2(*(__half2*)&raw.w);
            a0.x = fmaf(f0.x, av, a0.x); a0.y = fmaf(f0.y, av, a0.y);
            a0.z = fmaf(f1.x, av, a0.z); a0.w = fmaf(f1.y, av, a0.w);
            a1.x = fmaf(f2.x, av, a1.x); a1.y = fmaf(f2.y, av, a1.y);
            a1.z = fmaf(f3.x, av, a1.z); a1.w = fmaf(f3.y, av, a1.w);
        }
    }

    #pragma unroll
    for (int o = 16; o < 64; o <<= 1) {
        a0.x += __shfl_xor(a0.x, o); a0.y += __shfl_xor(a0.y, o);
        a0.z += __shfl_xor(a0.z, o); a0.w += __shfl_xor(a0.w, o);
        a1.x += __shfl_xor(a1.x, o); a1.y += __shfl_xor(a1.y, o);
        a1.z += __shfl_xor(a1.z, o); a1.w += __shfl_xor(a1.w, o);
    }

    if (q < 2) {
        int c = (ql << 3) + (q << 2);
        float4 r = q ? a1 : a0;
        float4 bv = *(const float4*)&bias[c];
        r.x += bv.x; r.y += bv.y; r.z += bv.z; r.w += bv.w;
        r.x = r.x > 0.f ? r.x : expm1f(r.x);
        r.y = r.y > 0.f ? r.y : expm1f(r.y);
        r.z = r.z > 0.f ? r.z : expm1f(r.z);
        r.w = r.w > 0.f ? r.w : expm1f(r.w);
        __half2 h0 = __floats2half2_rn(r.x, r.y);
        __half2 h1 = __floats2half2_rn(r.z, r.w);
        uint2 pk; pk.x = *(unsigned*)&h0; pk.y = *(unsigned*)&h1;
        *(uint2*)&zh[(size_t)wv*D_HID + c] = pk;
    }
}

// ---------------------------------------------------------------------------
// Semantic attention scores via MFMA; one atomicAdd per block into wsum[path].
__global__ __launch_bounds__(256) void sem_mfma(const __half* __restrict__ zh0,
                                                const __half* __restrict__ zh1,
                                                const __half* __restrict__ WP1T,
                                                const float* __restrict__ bp1,
                                                const float* __restrict__ Wp2,
                                                float* __restrict__ wsum) {
    __shared__ unsigned short zs[64][128];    // 16 KB
    __shared__ unsigned short ps[128][128];   // 32 KB
    __shared__ float red[4];
    const __half* z = blockIdx.y ? zh1 : zh0;
    int tid = threadIdx.x;
    int row0 = blockIdx.x * 64;
    int wid = tid >> 6, lane = tid & 63;
    int wm = wid >> 1, wn = wid & 1;
    int lr = lane & 15, lk = lane >> 4;

    #pragma unroll
    for (int i = 0; i < 4; ++i) {
        int id = tid + i*256;
        int r = id >> 4, ch = id & 15;
        int grow = row0 + r;
        uint4 pk = make_uint4(0u, 0u, 0u, 0u);
        if (grow < N_NODES) pk = *(const uint4*)&z[(size_t)grow*D_HID + (ch << 3)];
        *(uint4*)&zs[r][((ch ^ (r & 7)) << 3)] = pk;
    }
    #pragma unroll
    for (int i = 0; i < 16; ++i) {
        int id = tid + i*256;
        int c = id >> 5, k4 = (id & 31) << 2;
        uint2 pk = *(const uint2*)&WP1T[c*128 + k4];
        int cc = (((k4 >> 3) ^ (c & 7)) << 3) + (k4 & 7);
        *(uint2*)&ps[c][cc] = pk;
    }
    __syncthreads();

    floatx4 acc[2][4];
    #pragma unroll
    for (int m = 0; m < 2; ++m)
        #pragma unroll
        for (int n = 0; n < 4; ++n) acc[m][n] = (floatx4){0.f, 0.f, 0.f, 0.f};

    #pragma unroll
    for (int kk = 0; kk < 4; ++kk) {
        int ksub = kk*4 + lk;
        half8 a[2], b[4];
        #pragma unroll
        for (int m = 0; m < 2; ++m) {
            int r = wm*32 + m*16 + lr;
            a[m] = *(half8*)&zs[r][((ksub ^ (r & 7)) << 3)];
        }
        #pragma unroll
        for (int n = 0; n < 4; ++n) {
            int c = wn*64 + n*16 + lr;
            b[n] = *(half8*)&ps[c][((ksub ^ (c & 7)) << 3)];
        }
        #pragma unroll
        for (int m = 0; m < 2; ++m)
            #pragma unroll
            for (int n = 0; n < 4; ++n)
                acc[m][n] = __builtin_amdgcn_mfma_f32_16x16x32_f16(a[m], b[n], acc[m][n], 0, 0, 0);
    }

    float s = 0.f;
    #pragma unroll
    for (int m = 0; m < 2; ++m)
        #pragma unroll
        for (int n = 0; n < 4; ++n) {
            int col = wn*64 + n*16 + lr;
            float bp = bp1[col];
            float w2 = Wp2[col];
            #pragma unroll
            for (int r4 = 0; r4 < 4; ++r4) {
                int grow = row0 + wm*32 + m*16 + lk*4 + r4;
                if (grow < N_NODES) {
                    float v = acc[m][n][r4] + bp;
                    float t = 1.f - 2.f / (__expf(2.f*v) + 1.f);
                    s = fmaf(t, w2, s);
                }
            }
        }
    #pragma unroll
    for (int o = 1; o < 64; o <<= 1) s += __shfl_xor(s, o);
    if (lane == 0) red[wid] = s;
    __syncthreads();
    if (tid == 0) atomicAdd(&wsum[blockIdx.y], red[0] + red[1] + red[2] + red[3]);
}

// ---------------------------------------------------------------------------
// out[n,c] = bo[c] + sum_k (b0*z0[n,k] + b1*z1[n,k]) * Wo[k,c]; z inputs f16.
__global__ __launch_bounds__(256) void final_kernel(const __half* __restrict__ zh0,
                                                    const __half* __restrict__ zh1,
                                                    const float* __restrict__ Wo,
                                                    const float* __restrict__ bo,
                                                    const float* __restrict__ wsum,
                                                    float* __restrict__ out) {
    __shared__ float z0s[32][132];
    __shared__ float z1s[32][132];
    __shared__ float wos[128*8];
    __shared__ float bos[8];
    int tid = threadIdx.x;
    int n0 = blockIdx.x * 32;
    #pragma unroll
    for (int i = 0; i < 4; ++i) wos[tid + i*256] = Wo[tid + i*256];
    if (tid < 8) bos[tid] = bo[tid];
    #pragma unroll
    for (int i = 0; i < 2; ++i) {
        int id = tid + i*256;
        int r = id >> 4, c8 = (id & 15) << 3;
        uint4 p0 = *(const uint4*)&zh0[(size_t)(n0 + r)*D_HID + c8];
        uint4 p1 = *(const uint4*)&zh1[(size_t)(n0 + r)*D_HID + c8];
        float2 q0 = __half22float2(*(__half2*)&p0.x);
        float2 q1 = __half22float2(*(__half2*)&p0.y);
        float2 q2 = __half22float2(*(__half2*)&p0.z);
        float2 q3 = __half22float2(*(__half2*)&p0.w);
        *(float4*)&z0s[r][c8]     = make_float4(q0.x, q0.y, q1.x, q1.y);
        *(float4*)&z0s[r][c8 + 4] = make_float4(q2.x, q2.y, q3.x, q3.y);
        q0 = __half22float2(*(__half2*)&p1.x);
        q1 = __half22float2(*(__half2*)&p1.y);
        q2 = __half22float2(*(__half2*)&p1.z);
        q3 = __half22float2(*(__half2*)&p1.w);
        *(float4*)&z1s[r][c8]     = make_float4(q0.x, q0.y, q1.x, q1.y);
        *(float4*)&z1s[r][c8 + 4] = make_float4(q2.x, q2.y, q3.x, q3.y);
    }
    __syncthreads();

    float w0 = wsum[0] * (1.f / N_NODES), w1 = wsum[1] * (1.f / N_NODES);
    float m = fmaxf(w0, w1);
    float e0 = __expf(w0 - m), e1 = __expf(w1 - m);
    float b0 = e0 / (e0 + e1), b1 = 1.f - b0;

    int node = tid >> 3, c = tid & 7;
    float s = bos[c];
    #pragma unroll 8
    for (int k = 0; k < 128; ++k) {
        float hk = b0 * z0s[node][k] + b1 * z1s[node][k];
        s = fmaf(hk, wos[k*8 + c], s);
    }
    out[(n0 + node)*NC + c] = s;
}

// ---------------------------------------------------------------------------
extern "C" void kernel_launch(void* const* d_in, const int* in_sizes, int n_in,
                              void* d_out, int out_size, void* d_ws, size_t ws_size,
                              hipStream_t stream) {
    const float* x     = (const float*)d_in[0];
    const int*   src0  = (const int*)  d_in[1];
    const int*   dst0  = (const int*)  d_in[2];
    const float* ew0   = (const float*)d_in[3];
    const int*   src1  = (const int*)  d_in[4];
    const int*   dst1  = (const int*)  d_in[5];
    const float* ew1   = (const float*)d_in[6];
    const float* Wsrc0 = (const float*)d_in[7];
    const float* Wdst0 = (const float*)d_in[8];
    const float* al0   = (const float*)d_in[9];
    const float* ar0   = (const float*)d_in[10];
    const float* b0    = (const float*)d_in[11];
    const float* Wsrc1 = (const float*)d_in[12];
    const float* Wdst1 = (const float*)d_in[13];
    const float* al1   = (const float*)d_in[14];
    const float* ar1   = (const float*)d_in[15];
    const float* b1    = (const float*)d_in[16];
    const float* Wp1   = (const float*)d_in[17];
    const float* bp1   = (const float*)d_in[18];
    const float* Wp2   = (const float*)d_in[19];
    const float* Wo    = (const float*)d_in[20];
    const float* bo    = (const float*)d_in[21];
    float* out = (float*)d_out;

    // ---- workspace layout (4B float units). Serial = ~150 MB; fused adds a
    //      second EDG+BINNED (+40 MB -> ~190 MB). Runtime branch on ws_size.
    float*    ws     = (float*)d_ws;
    __half*   FS0    = (__half*)ws;                    // 25.6 MB
    __half*   FS1    = (__half*)(ws + 6400000);        // 25.6 MB
    __half*   ZH0    = (__half*)(ws + 12800000);       // 25.6 MB
    __half*   ZH1    = (__half*)(ws + 19200000);       // 25.6 MB
    float*    ELER   = ws + 25600000;                  // 6.4 MB
    float*    WSUM   = ELER + 1600000;                 // 8
    __half*   WTA    = (__half*)(WSUM + 8);            // 272*256 halves = 34816 floats
    __half*   WP1T   = (__half*)((float*)WTA + 34816); // 16384 halves = 8192 floats
    int*      CNT0   = (int*)((float*)WP1T + 8192);    // 100k
    int*      CNT1   = CNT0  + 100000;                 // 100k
    int*      GCUR0  = CNT1  + 100000;                 // 256
    int*      GCUR1  = GCUR0 + 256;                    // 256
    unsigned* EDG0   = (unsigned*)(GCUR1 + 256);       // 25.6 MB
    uint2*    BINNED0= (uint2*)(EDG0 + 6400000);       // 14.45 MB
    float*    endser = (float*)BINNED0 + 2*(size_t)BINS*BIN_CAP;
    unsigned* EDG1   = (unsigned*)endser;              // fused only: 25.6 MB
    uint2*    BINNED1= (uint2*)(EDG1 + 6400000);       // fused only: 14.45 MB
    size_t fused_bytes = (size_t)((float*)BINNED1 + 2*(size_t)BINS*BIN_CAP - ws) * 4;
    bool fused = ws_size >= fused_bytes;
    if (!fused) { EDG1 = EDG0; BINNED1 = BINNED0; }

    hipMemsetAsync(GCUR0, 0, sizeof(int)*512, stream);   // GCUR0+GCUR1 contiguous
    hipMemsetAsync(WSUM, 0, sizeof(float)*4, stream);

    prep<<<336, 256, 0, stream>>>(Wsrc0, Wsrc1, Wdst0, ar0, Wdst1, ar1, Wp1, WTA, WP1T);
    fs_all<<<(N_NODES + 31)/32, 256, 0, stream>>>(x, WTA, al0, al1, FS0, FS1, ELER);

    int nchunks = (N_EDGES + CHUNK - 1) / CHUNK;   // 196
    if (fused) {
        BinArgs ba = {{src0, src1}, {dst0, dst1}, {ew0, ew1},
                      {GCUR0, GCUR1}, {BINNED0, BINNED1}};
        bin_kernel<<<dim3(nchunks, 2), 1024, 0, stream>>>(ba);
        BucketArgs ka = {{GCUR0, GCUR1}, {BINNED0, BINNED1},
                         {CNT0, CNT1}, {EDG0, EDG1}};
        bucket_kernel<<<dim3(2*BINS, 2), 1024, 0, stream>>>(ka);
        agg_kernel<<<(N_NODES*64)/256, 256, 0, stream>>>(FS0, ELER, ELER + 400000, CNT0, EDG0, b0, ZH0);
        agg_kernel<<<(N_NODES*64)/256, 256, 0, stream>>>(FS1, ELER + 800000, ELER + 1200000, CNT1, EDG1, b1, ZH1);
    } else {
        BinArgs ba0 = {{src0, src0}, {dst0, dst0}, {ew0, ew0},
                       {GCUR0, GCUR0}, {BINNED0, BINNED0}};
        BucketArgs ka0 = {{GCUR0, GCUR0}, {BINNED0, BINNED0},
                          {CNT0, CNT0}, {EDG0, EDG0}};
        bin_kernel<<<dim3(nchunks, 1), 1024, 0, stream>>>(ba0);
        bucket_kernel<<<dim3(2*BINS, 1), 1024, 0, stream>>>(ka0);
        agg_kernel<<<(N_NODES*64)/256, 256, 0, stream>>>(FS0, ELER, ELER + 400000, CNT0, EDG0, b0, ZH0);
        BinArgs ba1 = {{src1, src1}, {dst1, dst1}, {ew1, ew1},
                       {GCUR1, GCUR1}, {BINNED0, BINNED0}};
        BucketArgs ka1 = {{GCUR1, GCUR1}, {BINNED0, BINNED0},
                          {CNT1, CNT1}, {EDG0, EDG0}};
        bin_kernel<<<dim3(nchunks, 1), 1024, 0, stream>>>(ba1);
        bucket_kernel<<<dim3(2*BINS, 1), 1024, 0, stream>>>(ka1);
        agg_kernel<<<(N_NODES*64)/256, 256, 0, stream>>>(FS1, ELER + 800000, ELER + 1200000, CNT1, EDG0, b1, ZH1);
    }

    // semantic attention + head
    dim3 semgrid((N_NODES + 63)/64, 2);
    sem_mfma<<<semgrid, 256, 0, stream>>>(ZH0, ZH1, WP1T, bp1, Wp2, WSUM);
    final_kernel<<<N_NODES/32, 256, 0, stream>>>(ZH0, ZH1, Wo, bo, WSUM, out);
}